// Round 10
// baseline (272.649 us; speedup 1.0000x reference)
//
#include <hip/hip_runtime.h>
#include <stdint.h>
#include <type_traits>

typedef __attribute__((ext_vector_type(8))) short bf16x8;
typedef __attribute__((ext_vector_type(4))) float f32x4;
typedef __attribute__((ext_vector_type(16))) float f32x16;

#define BB 4
#define NH 16
#define TT 2048
#define HD 64
#define CC 1024

__device__ __forceinline__ unsigned short f2bf(float f) {
  unsigned int u = __builtin_bit_cast(unsigned int, f);
  u += 0x7fff + ((u >> 16) & 1);
  return (unsigned short)(u >> 16);
}

__device__ __forceinline__ float fast_exp2(float x) {
#if __has_builtin(__builtin_amdgcn_exp2f)
  return __builtin_amdgcn_exp2f(x);
#else
  return exp2f(x);
#endif
}

__device__ __forceinline__ unsigned int cvtpk(float lo, float hi) {
  unsigned int r;
  asm("v_cvt_pk_bf16_f32 %0, %1, %2" : "=v"(r) : "v"(lo), "v"(hi));
  return r;
}

__device__ __forceinline__ void plswap(unsigned int& a, unsigned int& b) {
#if __has_builtin(__builtin_amdgcn_permlane32_swap)
  auto r = __builtin_amdgcn_permlane32_swap(a, b, false, false);
  a = r[0];
  b = r[1];
#else
  unsigned int as = __shfl_xor((int)a, 32), bs = __shfl_xor((int)b, 32);
  bool hi = (threadIdx.x & 32) != 0;
  unsigned int na = hi ? bs : a;
  unsigned int nb = hi ? b : as;
  a = na; b = nb;
#endif
}

__device__ __forceinline__ float partner32(float x, bool hi) {
  unsigned int a = __builtin_bit_cast(unsigned int, x), b = a;
  plswap(a, b);
  return __builtin_bit_cast(float, hi ? a : b);
}

__device__ __forceinline__ void g2l16(const void* g, void* s) {
  __builtin_amdgcn_global_load_lds(
      (const __attribute__((address_space(1))) unsigned int*)g,
      (__attribute__((address_space(3))) unsigned int*)s, 16, 0, 0);
}

// ---------------- fused cast f32 -> bf16 (x and features) ----------------
__global__ __launch_bounds__(256) void cast2(
    const float* __restrict__ x, const float* __restrict__ ft,
    unsigned short* __restrict__ xb, unsigned short* __restrict__ fb, int n) {
  const float* in = blockIdx.y ? ft : x;
  unsigned short* out = blockIdx.y ? fb : xb;
  int i = (blockIdx.x * 256 + threadIdx.x) * 4;
  if (i >= n) return;
  float4 v = *(const float4*)(in + i);
  ushort4 o;
  o.x = f2bf(v.x); o.y = f2bf(v.y); o.z = f2bf(v.z); o.w = f2bf(v.w);
  *(ushort4*)(out + i) = o;
}

// ---------------- mask -> float 0/1 ----------------
__global__ __launch_bounds__(256) void make_m01(
    const int* __restrict__ mask, float* __restrict__ m01, int n) {
  int i = blockIdx.x * 256 + threadIdx.x;
  if (i < n) m01[i] = mask[i] ? 1.0f : 0.0f;
}

// -------- fused weight transpose+cast: 4 weights in one launch ------------
__global__ __launch_bounds__(256) void transpose_cast_w4(
    const float* __restrict__ wq, const float* __restrict__ wk,
    const float* __restrict__ wv, const float* __restrict__ wo,
    unsigned short* __restrict__ wqkvt, unsigned short* __restrict__ wot) {
  __shared__ float tile[32][33];
  const int z = blockIdx.z;
  const float* w = (z == 0) ? wq : (z == 1) ? wk : (z == 2) ? wv : wo;
  unsigned short* wt = (z < 3) ? wqkvt + (size_t)z * CC * CC : wot;
  int nb = blockIdx.x * 32, kb = blockIdx.y * 32;
  int tx = threadIdx.x, ty = threadIdx.y;
#pragma unroll
  for (int r = ty; r < 32; r += 8)
    tile[r][tx] = w[(size_t)(kb + r) * CC + nb + tx];
  __syncthreads();
#pragma unroll
  for (int r = ty; r < 32; r += 8)
    wt[(size_t)(nb + r) * CC + kb + tx] = f2bf(tile[tx][r]);
}

// ---------------- QKV GEMM: 256x256 tile, 8 waves, phase-split -------------
// [8192][1024] @ Wt[3072][1024]^T. Sections: 0->Qb (scaled), 1->Kb,
// 2->Vtb (B,H,D,T; masked rows zeroed).
// LDS 64 KB: buf{0,1} x (A[256][32] + B[256][32]) bf16, XOR-swizzled
// (col ^= (row&3)<<4, write-side via pre-swizzled global source).
// Per K-tile: 2 phases x 16 MFMA, raw s_barrier (no drain) between;
// prefetch of tile k+1 issued at tile top; vmcnt(0) only at tile boundary.
__global__ __launch_bounds__(512) void gemm_qkv8(
    const unsigned short* __restrict__ xb, const unsigned short* __restrict__ fb,
    const unsigned short* __restrict__ Wt,
    const float* __restrict__ bq, const float* __restrict__ bk,
    const float* __restrict__ bv, const float* __restrict__ m01,
    unsigned short* __restrict__ Qb, unsigned short* __restrict__ Kb,
    unsigned short* __restrict__ Vtb, float qscale) {
  __shared__ __attribute__((aligned(128))) char lds[65536];
  const int t = threadIdx.x, l = t & 63, w = t >> 6;
  const int lr = l & 15, lg = l >> 4;
  const int wm = w >> 2, wn = w & 3;
  // XCD-bijective swizzle: 384 blocks = 8 * 48
  const int lin = blockIdx.x;
  const int sw = (lin & 7) * 48 + (lin >> 3);
  const int mt = sw & 31, nt = sw >> 5;
  const int m0 = mt * 256, n0g = nt * 256;
  const int sec = n0g >> 10, n0 = n0g & (CC - 1);
  const unsigned short* A = (sec == 0) ? xb : fb;

  // staging: thread t covers rows sR and sR+128 of the 256-row tile,
  // 16 B at col-bytes xsw (pre-swizzled source, linear LDS dest).
  const int sR = t >> 2;
  const int xsw = ((t & 3) * 16) ^ ((sR & 3) << 4);
  const unsigned short* gA = A + (size_t)(m0 + sR) * CC + (xsw >> 1);
  const unsigned short* gB = Wt + (size_t)(n0g + sR) * CC + (xsw >> 1);

  auto stage = [&](int bufb) {
    g2l16(gA,          lds + bufb + t * 16);
    g2l16(gA + 131072, lds + bufb + t * 16 + 8192);          // +128 rows
    g2l16(gB,          lds + bufb + 16384 + t * 16);
    g2l16(gB + 131072, lds + bufb + 16384 + t * 16 + 8192);
    gA += 32; gB += 32;   // advance one K-tile (32 elems)
  };

  // swizzled read offsets: row*64 + ((lg*16) ^ ((row&3)<<4)); row&3 == lr&3
  const int colx = (lg * 16) ^ ((lr & 3) << 4);
  const int aoff = (wm * 128 + lr) * 64 + colx;           // + mi*1024
  const int boff = 16384 + (wn * 64 + lr) * 64 + colx;    // + nj*1024

  f32x4 acc[8][4] = {};

  stage(0);  // prologue: K-tile 0 -> buf0
  asm volatile("s_waitcnt vmcnt(0)" ::: "memory");
  __syncthreads();

  auto tile = [&](auto BufC, bool doStage) {
    constexpr int BO = decltype(BufC)::value;  // 0 or 32768
    if (doStage) stage(BO ^ 32768);            // prefetch next tile early
    bf16x8 bf[4], af[4];
#pragma unroll
    for (int nj = 0; nj < 4; ++nj)
      bf[nj] = *(const bf16x8*)(lds + BO + boff + nj * 1024);
#pragma unroll
    for (int mi = 0; mi < 4; ++mi)
      af[mi] = *(const bf16x8*)(lds + BO + aoff + mi * 1024);
    __builtin_amdgcn_s_setprio(1);
#pragma unroll
    for (int mi = 0; mi < 4; ++mi)
#pragma unroll
      for (int nj = 0; nj < 4; ++nj)
        acc[mi][nj] = __builtin_amdgcn_mfma_f32_16x16x32_bf16(
            af[mi], bf[nj], acc[mi][nj], 0, 0, 0);
    __builtin_amdgcn_s_setprio(0);
    __builtin_amdgcn_sched_barrier(0);
    __builtin_amdgcn_s_barrier();              // phase boundary (no drain)
    __builtin_amdgcn_sched_barrier(0);
#pragma unroll
    for (int mi = 0; mi < 4; ++mi)
      af[mi] = *(const bf16x8*)(lds + BO + aoff + (mi + 4) * 1024);
    __builtin_amdgcn_s_setprio(1);
#pragma unroll
    for (int mi = 0; mi < 4; ++mi)
#pragma unroll
      for (int nj = 0; nj < 4; ++nj)
        acc[mi + 4][nj] = __builtin_amdgcn_mfma_f32_16x16x32_bf16(
            af[mi], bf[nj], acc[mi + 4][nj], 0, 0, 0);
    __builtin_amdgcn_s_setprio(0);
    __builtin_amdgcn_sched_barrier(0);
    asm volatile("s_waitcnt vmcnt(0)" ::: "memory");  // prefetched tile landed
    __builtin_amdgcn_s_barrier();              // tile boundary
    __builtin_amdgcn_sched_barrier(0);
  };

  for (int j = 0; j < 16; ++j) {
    tile(std::integral_constant<int, 0>{}, true);       // tile 2j, stage 2j+1
    tile(std::integral_constant<int, 32768>{}, j < 15); // tile 2j+1, stage 2j+2
  }

  // epilogue
  const float* bp = (sec == 0) ? bq : (sec == 1) ? bk : bv;
  const float scale = (sec == 0) ? qscale : 1.0f;
#pragma unroll
  for (int mi = 0; mi < 8; ++mi) {
#pragma unroll
    for (int nj = 0; nj < 4; ++nj) {
      int col = n0 + wn * 64 + nj * 16 + lr;
      float bias = bp[col];
#pragma unroll
      for (int jj = 0; jj < 4; ++jj) {
        int rowm = m0 + wm * 128 + mi * 16 + lg * 4 + jj;
        float v = (acc[mi][nj][jj] + bias) * scale;
        int b_ = rowm >> 11, tq = rowm & (TT - 1);
        int h_ = col >> 6, d_ = col & (HD - 1);
        if (sec < 2) {
          unsigned short* dst = (sec == 0) ? Qb : Kb;
          dst[((size_t)((b_ * NH + h_) * TT + tq) << 6) + d_] = f2bf(v);
        } else {
          v *= m01[rowm];  // zero V rows at masked tokens
          Vtb[((size_t)((b_ * NH + h_) * HD + d_) * TT) + tq] = f2bf(v);
        }
      }
    }
  }
}

// ---------------- O-projection GEMM (r8 single-buffer form) ----------------
__global__ __launch_bounds__(256) void gemm_out(
    const unsigned short* __restrict__ A, const unsigned short* __restrict__ Bt,
    const float* __restrict__ bias, float* __restrict__ Out) {
  __shared__ unsigned short As[128 * 32];
  __shared__ unsigned short Bs[128 * 32];
  int lin = blockIdx.y * gridDim.x + blockIdx.x;
  int cpx = (gridDim.x * gridDim.y) >> 3;
  int sw = (lin & 7) * cpx + (lin >> 3);
  const int n0 = (sw % 8) * 128;
  const int m0 = (sw / 8) * 128;
  const int t = threadIdx.x, l = t & 63, w = t >> 6;
  const int lr = l & 15, lg = l >> 4;
  const int wr = w >> 1, wc = w & 1;
  f32x4 acc[4][4] = {};
  for (int k0 = 0; k0 < CC; k0 += 32) {
#pragma unroll
    for (int i = 0; i < 2; ++i) {
      int c = w * 64 + l + i * 256;
      int row = c >> 2, cb = (c & 3) * 8;
      g2l16(A + (size_t)(m0 + row) * CC + k0 + cb, (char*)As + c * 16);
      g2l16(Bt + (size_t)(n0 + row) * CC + k0 + cb, (char*)Bs + c * 16);
    }
    __syncthreads();
    bf16x8 af[4], bfr[4];
#pragma unroll
    for (int mi = 0; mi < 4; ++mi)
      af[mi] = *(const bf16x8*)(As + (wr * 64 + mi * 16 + lr) * 32 + lg * 8);
#pragma unroll
    for (int nj = 0; nj < 4; ++nj)
      bfr[nj] = *(const bf16x8*)(Bs + (wc * 64 + nj * 16 + lr) * 32 + lg * 8);
#pragma unroll
    for (int mi = 0; mi < 4; ++mi)
#pragma unroll
      for (int nj = 0; nj < 4; ++nj)
        acc[mi][nj] = __builtin_amdgcn_mfma_f32_16x16x32_bf16(
            af[mi], bfr[nj], acc[mi][nj], 0, 0, 0);
    __syncthreads();
  }
#pragma unroll
  for (int mi = 0; mi < 4; ++mi) {
#pragma unroll
    for (int nj = 0; nj < 4; ++nj) {
      int col = n0 + wc * 64 + nj * 16 + lr;
      float bv = bias[col];
#pragma unroll
      for (int j = 0; j < 4; ++j) {
        int rowm = m0 + wr * 64 + mi * 16 + lg * 4 + j;
        Out[(size_t)rowm * CC + col] = acc[mi][nj][j] + bv;
      }
    }
  }
}

// ---------------- flash attention v8: scale-free softmax -------------------
__global__ __launch_bounds__(256) void attn_fwd8(
    const unsigned short* __restrict__ Q, const unsigned short* __restrict__ K,
    const unsigned short* __restrict__ Vt, const float* __restrict__ m01,
    unsigned short* __restrict__ O) {
  __shared__ __attribute__((aligned(64))) char ldsb[40960];
  const int t = threadIdx.x, l = t & 63, w = t >> 6;
  const int q5 = l & 31, hig = l >> 5;
  const bool hib = hig != 0;
  int lin = blockIdx.y * gridDim.x + blockIdx.x;
  int sw = (lin & 7) * 128 + (lin >> 3);
  const int bx = sw & 15, bh = sw >> 4;
  const int b_ = bh >> 4, h_ = bh & (NH - 1);
  const int q = bx * 128 + w * 32 + q5;
  const size_t base = (size_t)bh * TT * HD;
  const unsigned short* Kg = K + base;
  const unsigned short* Vg = Vt + (size_t)bh * HD * TT;

  bf16x8 qf[4];
  {
    const unsigned short* qp = Q + base + (size_t)q * HD + 8 * hig;
#pragma unroll
    for (int dk = 0; dk < 4; ++dk) qf[dk] = *(const bf16x8*)(qp + dk * 16);
  }

  int ka[4];
  {
    int swz = (q5 & 7) << 4;
#pragma unroll
    for (int dk = 0; dk < 4; ++dk)
      ka[dk] = q5 * 128 + ((dk * 32 + hig * 16) ^ swz);
  }
  int moff = 32768 + hig * 16;

  const int s1 = t + 256;
  const int r0 = t >> 3, c0 = (t & 7) * 16, x0 = c0 ^ ((r0 & 7) << 4);
  const int r1 = s1 >> 3, c1 = (s1 & 7) * 16, x1 = c1 ^ ((r1 & 7) << 4);
  const unsigned short* gk0 = Kg + r0 * HD + (x0 >> 1);
  const unsigned short* gk1 = Kg + r1 * HD + (x1 >> 1);
  const unsigned short* gv0 = Vg + (size_t)r0 * TT + (x0 >> 1);
  const unsigned short* gv1 = Vg + (size_t)r1 * TT + (x1 >> 1);

  auto stage = [&](int boff) {
    g2l16(gk0, ldsb + t * 16 + boff);
    g2l16(gk1, ldsb + t * 16 + 4096 + boff);
    g2l16(gv0, ldsb + 16384 + t * 16 + boff);
    g2l16(gv1, ldsb + 16384 + t * 16 + 4096 + boff);
    gk0 += 4096; gk1 += 4096; gv0 += 64; gv1 += 64;
  };

  f32x16 ot[2];
#pragma unroll
  for (int i = 0; i < 16; ++i) { ot[0][i] = 0.f; ot[1][i] = 0.f; }
  float l0 = 0.f, l1 = 0.f, l2 = 0.f, l3 = 0.f;

  {
    const float* mg = m01 + (size_t)b_ * TT;
#pragma unroll
    for (int i = 0; i < 2; ++i) {
      int s = t + i * 256;
      g2l16(mg + s * 4, ldsb + 32768 + s * 16);
    }
  }
  stage(0);
  asm volatile("s_waitcnt vmcnt(0)" ::: "memory");
  __syncthreads();

  auto compute = [&](auto Bc) {
    constexpr int BO = decltype(Bc)::value;
    constexpr int MO = BO ? 256 : 0;
    f32x16 s[2] = {};
    __builtin_amdgcn_s_setprio(1);
#pragma unroll
    for (int dk = 0; dk < 4; ++dk) {
      bf16x8 kf0 = *(const bf16x8*)(ldsb + ka[dk] + BO);
      bf16x8 kf1 = *(const bf16x8*)(ldsb + ka[dk] + 4096 + BO);
      s[0] = __builtin_amdgcn_mfma_f32_32x32x16_bf16(kf0, qf[dk], s[0], 0, 0, 0);
      s[1] = __builtin_amdgcn_mfma_f32_32x32x16_bf16(kf1, qf[dk], s[1], 0, 0, 0);
    }
    __builtin_amdgcn_s_setprio(0);

    unsigned int wl[2][4], wh[2][4];
#pragma unroll
    for (int kk = 0; kk < 2; ++kk)
#pragma unroll
      for (int g = 0; g < 4; ++g) {
        int i = g * 4;
        float e0 = fast_exp2(s[kk][i + 0]);
        float e1 = fast_exp2(s[kk][i + 1]);
        float e2 = fast_exp2(s[kk][i + 2]);
        float e3 = fast_exp2(s[kk][i + 3]);
        f32x4 mk = *(const f32x4*)(ldsb + moff + MO + kk * 128 + g * 32);
        l0 = fmaf(e0, mk[0], l0);
        l1 = fmaf(e1, mk[1], l1);
        l2 = fmaf(e2, mk[2], l2);
        l3 = fmaf(e3, mk[3], l3);
        wl[kk][g] = cvtpk(e0, e1);
        wh[kk][g] = cvtpk(e2, e3);
      }

    bf16x8 pa[4];
#pragma unroll
    for (int ks = 0; ks < 4; ++ks) {
      const int kk = ks >> 1, gA = 2 * (ks & 1), gB = gA + 1;
      unsigned int a0 = wl[kk][gA], b0 = wl[kk][gB];
      unsigned int a1 = wh[kk][gA], b1 = wh[kk][gB];
      plswap(a0, b0);
      plswap(a1, b1);
      unsigned int pw[4] = {a0, a1, b0, b1};
      pa[ks] = *(bf16x8*)pw;
    }

    __builtin_amdgcn_s_setprio(1);
#pragma unroll
    for (int ks = 0; ks < 4; ++ks) {
      bf16x8 vf0 = *(const bf16x8*)(ldsb + ka[ks] + 16384 + BO);
      bf16x8 vf1 = *(const bf16x8*)(ldsb + ka[ks] + 16384 + 4096 + BO);
      ot[0] = __builtin_amdgcn_mfma_f32_32x32x16_bf16(vf0, pa[ks], ot[0], 0, 0, 0);
      ot[1] = __builtin_amdgcn_mfma_f32_32x32x16_bf16(vf1, pa[ks], ot[1], 0, 0, 0);
    }
    __builtin_amdgcn_s_setprio(0);
  };

  for (int j = 0; j < 16; ++j) {
    stage(8192);
    compute(std::integral_constant<int, 0>{});
    asm volatile("s_waitcnt vmcnt(0)" ::: "memory");
    __syncthreads();
    if (j < 15) stage(0);
    compute(std::integral_constant<int, 8192>{});
    asm volatile("s_waitcnt vmcnt(0)" ::: "memory");
    __syncthreads();
    moff += 512;
  }

  float l_ = (l0 + l1) + (l2 + l3);
  float l_tot = l_ + partner32(l_, hib);
  const float inv = 1.f / l_tot;
  unsigned short* orow = O + ((size_t)(b_ * TT) + q) * CC + h_ * 64 + 4 * hig;
#pragma unroll
  for (int dt = 0; dt < 2; ++dt)
#pragma unroll
    for (int g = 0; g < 4; ++g) {
      unsigned short pk4[4];
#pragma unroll
      for (int j = 0; j < 4; ++j) pk4[j] = f2bf(ot[dt][4 * g + j] * inv);
      *(ushort4*)(orow + dt * 32 + 8 * g) = *(ushort4*)pk4;
    }
}

extern "C" void kernel_launch(void* const* d_in, const int* in_sizes, int n_in,
                              void* d_out, int out_size, void* d_ws, size_t ws_size,
                              hipStream_t stream) {
  const float* x  = (const float*)d_in[0];
  const float* ft = (const float*)d_in[1];
  const int* mask = (const int*)d_in[2];
  const float* wq = (const float*)d_in[3];
  const float* bq = (const float*)d_in[4];
  const float* wk = (const float*)d_in[5];
  const float* bk = (const float*)d_in[6];
  const float* wv = (const float*)d_in[7];
  const float* bv = (const float*)d_in[8];
  const float* wo = (const float*)d_in[9];
  const float* bo = (const float*)d_in[10];
  float* out = (float*)d_out;

  char* ws = (char*)d_ws;
  const size_t NTOK = (size_t)BB * TT;   // 8192
  const size_t SB = NTOK * CC * 2;       // 16 MiB
  unsigned short* xb   = (unsigned short*)ws; ws += SB;
  unsigned short* fb   = (unsigned short*)ws; ws += SB;
  unsigned short* Qb   = (unsigned short*)ws; ws += SB;
  unsigned short* Kb   = (unsigned short*)ws; ws += SB;
  unsigned short* Vtb  = (unsigned short*)ws; ws += SB;   // V^T (b,h,d,t)
  unsigned short* AO   = (unsigned short*)ws; ws += SB;
  unsigned short* wqkvt = (unsigned short*)ws; ws += (size_t)3 * CC * CC * 2;
  unsigned short* wot   = (unsigned short*)ws; ws += (size_t)CC * CC * 2;
  float* m01 = (float*)ws; ws += NTOK * 4;

  int ncast = (int)(NTOK * CC);
  dim3 gc(ncast / 4 / 256, 2);
  cast2<<<gc, 256, 0, stream>>>(x, ft, xb, fb, ncast);
  dim3 tb(32, 8), tg(32, 32, 4);
  transpose_cast_w4<<<tg, tb, 0, stream>>>(wq, wk, wv, wo, wqkvt, wot);
  make_m01<<<(int)(NTOK / 256), 256, 0, stream>>>(mask, m01, (int)NTOK);

  const float qscale = 0.125f * 1.44269504f;  // 1/sqrt(64) * log2(e)
  gemm_qkv8<<<384, 512, 0, stream>>>(xb, fb, wqkvt, bq, bk, bv, m01,
                                     Qb, Kb, Vtb, qscale);

  dim3 ga(16, 64);  // 1024 blocks
  attn_fwd8<<<ga, 256, 0, stream>>>(Qb, Kb, Vtb, m01, AO);

  dim3 go(8, 64);   // 512 blocks
  gemm_out<<<go, 256, 0, stream>>>(AO, wot, bo, out);
}

// Round 11
// 237.089 us; speedup vs baseline: 1.1500x; 1.1500x over previous
//
#include <hip/hip_runtime.h>
#include <stdint.h>
#include <type_traits>

typedef __attribute__((ext_vector_type(8))) short bf16x8;
typedef __attribute__((ext_vector_type(4))) float f32x4;
typedef __attribute__((ext_vector_type(16))) float f32x16;

#define BB 4
#define NH 16
#define TT 2048
#define HD 64
#define CC 1024

__device__ __forceinline__ unsigned short f2bf(float f) {
  unsigned int u = __builtin_bit_cast(unsigned int, f);
  u += 0x7fff + ((u >> 16) & 1);
  return (unsigned short)(u >> 16);
}

__device__ __forceinline__ float fast_exp2(float x) {
#if __has_builtin(__builtin_amdgcn_exp2f)
  return __builtin_amdgcn_exp2f(x);
#else
  return exp2f(x);
#endif
}

__device__ __forceinline__ unsigned int cvtpk(float lo, float hi) {
  unsigned int r;
  asm("v_cvt_pk_bf16_f32 %0, %1, %2" : "=v"(r) : "v"(lo), "v"(hi));
  return r;
}

__device__ __forceinline__ void plswap(unsigned int& a, unsigned int& b) {
#if __has_builtin(__builtin_amdgcn_permlane32_swap)
  auto r = __builtin_amdgcn_permlane32_swap(a, b, false, false);
  a = r[0];
  b = r[1];
#else
  unsigned int as = __shfl_xor((int)a, 32), bs = __shfl_xor((int)b, 32);
  bool hi = (threadIdx.x & 32) != 0;
  unsigned int na = hi ? bs : a;
  unsigned int nb = hi ? b : as;
  a = na; b = nb;
#endif
}

__device__ __forceinline__ float partner32(float x, bool hi) {
  unsigned int a = __builtin_bit_cast(unsigned int, x), b = a;
  plswap(a, b);
  return __builtin_bit_cast(float, hi ? a : b);
}

__device__ __forceinline__ void g2l16(const void* g, void* s) {
  __builtin_amdgcn_global_load_lds(
      (const __attribute__((address_space(1))) unsigned int*)g,
      (__attribute__((address_space(3))) unsigned int*)s, 16, 0, 0);
}

// ---------------- fused cast f32 -> bf16 (x and features) ----------------
__global__ __launch_bounds__(256) void cast2(
    const float* __restrict__ x, const float* __restrict__ ft,
    unsigned short* __restrict__ xb, unsigned short* __restrict__ fb, int n) {
  const float* in = blockIdx.y ? ft : x;
  unsigned short* out = blockIdx.y ? fb : xb;
  int i = (blockIdx.x * 256 + threadIdx.x) * 4;
  if (i >= n) return;
  float4 v = *(const float4*)(in + i);
  ushort4 o;
  o.x = f2bf(v.x); o.y = f2bf(v.y); o.z = f2bf(v.z); o.w = f2bf(v.w);
  *(ushort4*)(out + i) = o;
}

// ---------------- mask -> float 0/1 ----------------
__global__ __launch_bounds__(256) void make_m01(
    const int* __restrict__ mask, float* __restrict__ m01, int n) {
  int i = blockIdx.x * 256 + threadIdx.x;
  if (i < n) m01[i] = mask[i] ? 1.0f : 0.0f;
}

// -------- fused weight transpose+cast: 4 weights in one launch ------------
__global__ __launch_bounds__(256) void transpose_cast_w4(
    const float* __restrict__ wq, const float* __restrict__ wk,
    const float* __restrict__ wv, const float* __restrict__ wo,
    unsigned short* __restrict__ wqkvt, unsigned short* __restrict__ wot) {
  __shared__ float tile[32][33];
  const int z = blockIdx.z;
  const float* w = (z == 0) ? wq : (z == 1) ? wk : (z == 2) ? wv : wo;
  unsigned short* wt = (z < 3) ? wqkvt + (size_t)z * CC * CC : wot;
  int nb = blockIdx.x * 32, kb = blockIdx.y * 32;
  int tx = threadIdx.x, ty = threadIdx.y;
#pragma unroll
  for (int r = ty; r < 32; r += 8)
    tile[r][tx] = w[(size_t)(kb + r) * CC + nb + tx];
  __syncthreads();
#pragma unroll
  for (int r = ty; r < 32; r += 8)
    wt[(size_t)(nb + r) * CC + kb + tx] = f2bf(tile[tx][r]);
}

// ---------------- fused QKV GEMM: BK=64, swizzled LDS ----------------------
// [8192][1024] @ Wt[3072][1024]^T. Sections: 0->Qb (scaled), 1->Kb,
// 2->Vtb (B,H,D,T; masked rows zeroed).
// LDS 32 KB: As[128][64], Bs[128][64] bf16; 128-B rows XOR-swizzled
// (byte col ^= (row&7)<<4) via pre-swizzled global source, linear dest.
// 16 K-iterations; 32 MFMA per drain+barrier pair (vs 16 at BK=32).
__global__ __launch_bounds__(256) void gemm_qkv(
    const unsigned short* __restrict__ xb, const unsigned short* __restrict__ fb,
    const unsigned short* __restrict__ Wt,
    const float* __restrict__ bq, const float* __restrict__ bk,
    const float* __restrict__ bv, const float* __restrict__ m01,
    unsigned short* __restrict__ Qb, unsigned short* __restrict__ Kb,
    unsigned short* __restrict__ Vtb, float qscale) {
  __shared__ unsigned short As[128 * 64];
  __shared__ unsigned short Bs[128 * 64];
  int lin = blockIdx.y * gridDim.x + blockIdx.x;
  int cpx = (gridDim.x * gridDim.y) >> 3;
  int sw = (lin & 7) * cpx + (lin >> 3);
  const int n0g = (sw % 24) * 128;
  const int m0 = (sw / 24) * 128;
  const int sec = n0g >> 10;
  const int n0 = n0g & (CC - 1);
  const unsigned short* A = (sec == 0) ? xb : fb;
  const unsigned short* Bt = Wt + (size_t)n0g * CC;

  const int t = threadIdx.x, l = t & 63, w = t >> 6;
  const int lr = l & 15, lg = l >> 4;
  const int wr = w >> 1, wc = w & 1;

  // staging: 1024 chunks of 16 B per matrix; thread t covers rows
  // sR+{0,32,64,96} at pre-swizzled col bytes sx (row&7 identical for all 4).
  const int sR = t >> 3;
  const int sx = ((t & 7) * 16) ^ ((sR & 7) << 4);
  const unsigned short* gA = A + (size_t)(m0 + sR) * CC + (sx >> 1);
  const unsigned short* gB = Bt + (size_t)sR * CC + (sx >> 1);
  auto stage = [&]() {
#pragma unroll
    for (int i = 0; i < 4; ++i) {
      g2l16(gA + (size_t)(i * 32) * CC, (char*)As + t * 16 + i * 4096);
      g2l16(gB + (size_t)(i * 32) * CC, (char*)Bs + t * 16 + i * 4096);
    }
    gA += 64; gB += 64;  // advance one K-tile
  };

  // swizzled read offsets: row r -> r*128 + ((kk*64 + lg*16) ^ ((lr&7)<<4))
  const int axs = (lr & 7) << 4;
  const int col0 = (lg * 16) ^ axs;
  const int col1 = (64 + lg * 16) ^ axs;
  const int abase = (wr * 64 + lr) * 128;  // + mi*2048 + colK
  const int bbase = (wc * 64 + lr) * 128;  // + nj*2048 + colK

  f32x4 acc[4][4] = {};
  for (int j = 0; j < 16; ++j) {
    stage();
    asm volatile("s_waitcnt vmcnt(0)" ::: "memory");
    __syncthreads();
    bf16x8 af[4], bfr[4];
#pragma unroll
    for (int mi = 0; mi < 4; ++mi)
      af[mi] = *(const bf16x8*)((const char*)As + abase + mi * 2048 + col0);
#pragma unroll
    for (int nj = 0; nj < 4; ++nj)
      bfr[nj] = *(const bf16x8*)((const char*)Bs + bbase + nj * 2048 + col0);
#pragma unroll
    for (int mi = 0; mi < 4; ++mi)
#pragma unroll
      for (int nj = 0; nj < 4; ++nj)
        acc[mi][nj] = __builtin_amdgcn_mfma_f32_16x16x32_bf16(
            af[mi], bfr[nj], acc[mi][nj], 0, 0, 0);
#pragma unroll
    for (int mi = 0; mi < 4; ++mi)
      af[mi] = *(const bf16x8*)((const char*)As + abase + mi * 2048 + col1);
#pragma unroll
    for (int nj = 0; nj < 4; ++nj)
      bfr[nj] = *(const bf16x8*)((const char*)Bs + bbase + nj * 2048 + col1);
#pragma unroll
    for (int mi = 0; mi < 4; ++mi)
#pragma unroll
      for (int nj = 0; nj < 4; ++nj)
        acc[mi][nj] = __builtin_amdgcn_mfma_f32_16x16x32_bf16(
            af[mi], bfr[nj], acc[mi][nj], 0, 0, 0);
    __syncthreads();
  }

  const float* bp = (sec == 0) ? bq : (sec == 1) ? bk : bv;
  const float scale = (sec == 0) ? qscale : 1.0f;
#pragma unroll
  for (int mi = 0; mi < 4; ++mi) {
#pragma unroll
    for (int nj = 0; nj < 4; ++nj) {
      int col = n0 + wc * 64 + nj * 16 + lr;
      float bias = bp[col];
#pragma unroll
      for (int j = 0; j < 4; ++j) {
        int rowm = m0 + wr * 64 + mi * 16 + lg * 4 + j;
        float v = (acc[mi][nj][j] + bias) * scale;
        int b_ = rowm >> 11, tq = rowm & (TT - 1);
        int h_ = col >> 6, d_ = col & (HD - 1);
        if (sec < 2) {
          unsigned short* dst = (sec == 0) ? Qb : Kb;
          dst[((size_t)((b_ * NH + h_) * TT + tq) << 6) + d_] = f2bf(v);
        } else {
          v *= m01[rowm];  // zero V rows at masked tokens (mask -> PV for free)
          Vtb[((size_t)((b_ * NH + h_) * HD + d_) * TT) + tq] = f2bf(v);
        }
      }
    }
  }
}

// ---------------- O-projection GEMM: BK=64, swizzled LDS ------------------
__global__ __launch_bounds__(256) void gemm_out(
    const unsigned short* __restrict__ A, const unsigned short* __restrict__ Bt,
    const float* __restrict__ bias, float* __restrict__ Out) {
  __shared__ unsigned short As[128 * 64];
  __shared__ unsigned short Bs[128 * 64];
  int lin = blockIdx.y * gridDim.x + blockIdx.x;
  int cpx = (gridDim.x * gridDim.y) >> 3;
  int sw = (lin & 7) * cpx + (lin >> 3);
  const int n0 = (sw % 8) * 128;
  const int m0 = (sw / 8) * 128;
  const int t = threadIdx.x, l = t & 63, w = t >> 6;
  const int lr = l & 15, lg = l >> 4;
  const int wr = w >> 1, wc = w & 1;

  const int sR = t >> 3;
  const int sx = ((t & 7) * 16) ^ ((sR & 7) << 4);
  const unsigned short* gA = A + (size_t)(m0 + sR) * CC + (sx >> 1);
  const unsigned short* gB = Bt + (size_t)(n0 + sR) * CC + (sx >> 1);
  auto stage = [&]() {
#pragma unroll
    for (int i = 0; i < 4; ++i) {
      g2l16(gA + (size_t)(i * 32) * CC, (char*)As + t * 16 + i * 4096);
      g2l16(gB + (size_t)(i * 32) * CC, (char*)Bs + t * 16 + i * 4096);
    }
    gA += 64; gB += 64;
  };

  const int axs = (lr & 7) << 4;
  const int col0 = (lg * 16) ^ axs;
  const int col1 = (64 + lg * 16) ^ axs;
  const int abase = (wr * 64 + lr) * 128;
  const int bbase = (wc * 64 + lr) * 128;

  f32x4 acc[4][4] = {};
  for (int j = 0; j < 16; ++j) {
    stage();
    asm volatile("s_waitcnt vmcnt(0)" ::: "memory");
    __syncthreads();
    bf16x8 af[4], bfr[4];
#pragma unroll
    for (int mi = 0; mi < 4; ++mi)
      af[mi] = *(const bf16x8*)((const char*)As + abase + mi * 2048 + col0);
#pragma unroll
    for (int nj = 0; nj < 4; ++nj)
      bfr[nj] = *(const bf16x8*)((const char*)Bs + bbase + nj * 2048 + col0);
#pragma unroll
    for (int mi = 0; mi < 4; ++mi)
#pragma unroll
      for (int nj = 0; nj < 4; ++nj)
        acc[mi][nj] = __builtin_amdgcn_mfma_f32_16x16x32_bf16(
            af[mi], bfr[nj], acc[mi][nj], 0, 0, 0);
#pragma unroll
    for (int mi = 0; mi < 4; ++mi)
      af[mi] = *(const bf16x8*)((const char*)As + abase + mi * 2048 + col1);
#pragma unroll
    for (int nj = 0; nj < 4; ++nj)
      bfr[nj] = *(const bf16x8*)((const char*)Bs + bbase + nj * 2048 + col1);
#pragma unroll
    for (int mi = 0; mi < 4; ++mi)
#pragma unroll
      for (int nj = 0; nj < 4; ++nj)
        acc[mi][nj] = __builtin_amdgcn_mfma_f32_16x16x32_bf16(
            af[mi], bfr[nj], acc[mi][nj], 0, 0, 0);
    __syncthreads();
  }

#pragma unroll
  for (int mi = 0; mi < 4; ++mi) {
#pragma unroll
    for (int nj = 0; nj < 4; ++nj) {
      int col = n0 + wc * 64 + nj * 16 + lr;
      float bv = bias[col];
#pragma unroll
      for (int j = 0; j < 4; ++j) {
        int rowm = m0 + wr * 64 + mi * 16 + lg * 4 + j;
        Out[(size_t)rowm * CC + col] = acc[mi][nj][j] + bv;
      }
    }
  }
}

// ---------------- flash attention v8: scale-free softmax (r8, unchanged) ---
__global__ __launch_bounds__(256) void attn_fwd8(
    const unsigned short* __restrict__ Q, const unsigned short* __restrict__ K,
    const unsigned short* __restrict__ Vt, const float* __restrict__ m01,
    unsigned short* __restrict__ O) {
  __shared__ __attribute__((aligned(64))) char ldsb[40960];
  const int t = threadIdx.x, l = t & 63, w = t >> 6;
  const int q5 = l & 31, hig = l >> 5;
  const bool hib = hig != 0;
  int lin = blockIdx.y * gridDim.x + blockIdx.x;
  int sw = (lin & 7) * 128 + (lin >> 3);
  const int bx = sw & 15, bh = sw >> 4;
  const int b_ = bh >> 4, h_ = bh & (NH - 1);
  const int q = bx * 128 + w * 32 + q5;
  const size_t base = (size_t)bh * TT * HD;
  const unsigned short* Kg = K + base;
  const unsigned short* Vg = Vt + (size_t)bh * HD * TT;

  bf16x8 qf[4];
  {
    const unsigned short* qp = Q + base + (size_t)q * HD + 8 * hig;
#pragma unroll
    for (int dk = 0; dk < 4; ++dk) qf[dk] = *(const bf16x8*)(qp + dk * 16);
  }

  int ka[4];
  {
    int swz = (q5 & 7) << 4;
#pragma unroll
    for (int dk = 0; dk < 4; ++dk)
      ka[dk] = q5 * 128 + ((dk * 32 + hig * 16) ^ swz);
  }
  int moff = 32768 + hig * 16;

  const int s1 = t + 256;
  const int r0 = t >> 3, c0 = (t & 7) * 16, x0 = c0 ^ ((r0 & 7) << 4);
  const int r1 = s1 >> 3, c1 = (s1 & 7) * 16, x1 = c1 ^ ((r1 & 7) << 4);
  const unsigned short* gk0 = Kg + r0 * HD + (x0 >> 1);
  const unsigned short* gk1 = Kg + r1 * HD + (x1 >> 1);
  const unsigned short* gv0 = Vg + (size_t)r0 * TT + (x0 >> 1);
  const unsigned short* gv1 = Vg + (size_t)r1 * TT + (x1 >> 1);

  auto stage = [&](int boff) {
    g2l16(gk0, ldsb + t * 16 + boff);
    g2l16(gk1, ldsb + t * 16 + 4096 + boff);
    g2l16(gv0, ldsb + 16384 + t * 16 + boff);
    g2l16(gv1, ldsb + 16384 + t * 16 + 4096 + boff);
    gk0 += 4096; gk1 += 4096; gv0 += 64; gv1 += 64;
  };

  f32x16 ot[2];
#pragma unroll
  for (int i = 0; i < 16; ++i) { ot[0][i] = 0.f; ot[1][i] = 0.f; }
  float l0 = 0.f, l1 = 0.f, l2 = 0.f, l3 = 0.f;

  {
    const float* mg = m01 + (size_t)b_ * TT;
#pragma unroll
    for (int i = 0; i < 2; ++i) {
      int s = t + i * 256;
      g2l16(mg + s * 4, ldsb + 32768 + s * 16);
    }
  }
  stage(0);
  asm volatile("s_waitcnt vmcnt(0)" ::: "memory");
  __syncthreads();

  auto compute = [&](auto Bc) {
    constexpr int BO = decltype(Bc)::value;
    constexpr int MO = BO ? 256 : 0;
    f32x16 s[2] = {};
    __builtin_amdgcn_s_setprio(1);
#pragma unroll
    for (int dk = 0; dk < 4; ++dk) {
      bf16x8 kf0 = *(const bf16x8*)(ldsb + ka[dk] + BO);
      bf16x8 kf1 = *(const bf16x8*)(ldsb + ka[dk] + 4096 + BO);
      s[0] = __builtin_amdgcn_mfma_f32_32x32x16_bf16(kf0, qf[dk], s[0], 0, 0, 0);
      s[1] = __builtin_amdgcn_mfma_f32_32x32x16_bf16(kf1, qf[dk], s[1], 0, 0, 0);
    }
    __builtin_amdgcn_s_setprio(0);

    unsigned int wl[2][4], wh[2][4];
#pragma unroll
    for (int kk = 0; kk < 2; ++kk)
#pragma unroll
      for (int g = 0; g < 4; ++g) {
        int i = g * 4;
        float e0 = fast_exp2(s[kk][i + 0]);
        float e1 = fast_exp2(s[kk][i + 1]);
        float e2 = fast_exp2(s[kk][i + 2]);
        float e3 = fast_exp2(s[kk][i + 3]);
        f32x4 mk = *(const f32x4*)(ldsb + moff + MO + kk * 128 + g * 32);
        l0 = fmaf(e0, mk[0], l0);
        l1 = fmaf(e1, mk[1], l1);
        l2 = fmaf(e2, mk[2], l2);
        l3 = fmaf(e3, mk[3], l3);
        wl[kk][g] = cvtpk(e0, e1);
        wh[kk][g] = cvtpk(e2, e3);
      }

    bf16x8 pa[4];
#pragma unroll
    for (int ks = 0; ks < 4; ++ks) {
      const int kk = ks >> 1, gA = 2 * (ks & 1), gB = gA + 1;
      unsigned int a0 = wl[kk][gA], b0 = wl[kk][gB];
      unsigned int a1 = wh[kk][gA], b1 = wh[kk][gB];
      plswap(a0, b0);
      plswap(a1, b1);
      unsigned int pw[4] = {a0, a1, b0, b1};
      pa[ks] = *(bf16x8*)pw;
    }

    __builtin_amdgcn_s_setprio(1);
#pragma unroll
    for (int ks = 0; ks < 4; ++ks) {
      bf16x8 vf0 = *(const bf16x8*)(ldsb + ka[ks] + 16384 + BO);
      bf16x8 vf1 = *(const bf16x8*)(ldsb + ka[ks] + 16384 + 4096 + BO);
      ot[0] = __builtin_amdgcn_mfma_f32_32x32x16_bf16(vf0, pa[ks], ot[0], 0, 0, 0);
      ot[1] = __builtin_amdgcn_mfma_f32_32x32x16_bf16(vf1, pa[ks], ot[1], 0, 0, 0);
    }
    __builtin_amdgcn_s_setprio(0);
  };

  for (int j = 0; j < 16; ++j) {
    stage(8192);
    compute(std::integral_constant<int, 0>{});
    asm volatile("s_waitcnt vmcnt(0)" ::: "memory");
    __syncthreads();
    if (j < 15) stage(0);
    compute(std::integral_constant<int, 8192>{});
    asm volatile("s_waitcnt vmcnt(0)" ::: "memory");
    __syncthreads();
    moff += 512;
  }

  float l_ = (l0 + l1) + (l2 + l3);
  float l_tot = l_ + partner32(l_, hib);
  const float inv = 1.f / l_tot;
  unsigned short* orow = O + ((size_t)(b_ * TT) + q) * CC + h_ * 64 + 4 * hig;
#pragma unroll
  for (int dt = 0; dt < 2; ++dt)
#pragma unroll
    for (int g = 0; g < 4; ++g) {
      unsigned short pk4[4];
#pragma unroll
      for (int j = 0; j < 4; ++j) pk4[j] = f2bf(ot[dt][4 * g + j] * inv);
      *(ushort4*)(orow + dt * 32 + 8 * g) = *(ushort4*)pk4;
    }
}

extern "C" void kernel_launch(void* const* d_in, const int* in_sizes, int n_in,
                              void* d_out, int out_size, void* d_ws, size_t ws_size,
                              hipStream_t stream) {
  const float* x  = (const float*)d_in[0];
  const float* ft = (const float*)d_in[1];
  const int* mask = (const int*)d_in[2];
  const float* wq = (const float*)d_in[3];
  const float* bq = (const float*)d_in[4];
  const float* wk = (const float*)d_in[5];
  const float* bk = (const float*)d_in[6];
  const float* wv = (const float*)d_in[7];
  const float* bv = (const float*)d_in[8];
  const float* wo = (const float*)d_in[9];
  const float* bo = (const float*)d_in[10];
  float* out = (float*)d_out;

  char* ws = (char*)d_ws;
  const size_t NTOK = (size_t)BB * TT;   // 8192
  const size_t SB = NTOK * CC * 2;       // 16 MiB
  unsigned short* xb   = (unsigned short*)ws; ws += SB;
  unsigned short* fb   = (unsigned short*)ws; ws += SB;
  unsigned short* Qb   = (unsigned short*)ws; ws += SB;
  unsigned short* Kb   = (unsigned short*)ws; ws += SB;
  unsigned short* Vtb  = (unsigned short*)ws; ws += SB;   // V^T (b,h,d,t)
  unsigned short* AO   = (unsigned short*)ws; ws += SB;
  unsigned short* wqkvt = (unsigned short*)ws; ws += (size_t)3 * CC * CC * 2;
  unsigned short* wot   = (unsigned short*)ws; ws += (size_t)CC * CC * 2;
  float* m01 = (float*)ws; ws += NTOK * 4;

  int ncast = (int)(NTOK * CC);
  dim3 gc(ncast / 4 / 256, 2);
  cast2<<<gc, 256, 0, stream>>>(x, ft, xb, fb, ncast);
  dim3 tb(32, 8), tg(32, 32, 4);
  transpose_cast_w4<<<tg, tb, 0, stream>>>(wq, wk, wv, wo, wqkvt, wot);
  make_m01<<<(int)(NTOK / 256), 256, 0, stream>>>(mask, m01, (int)NTOK);

  const float qscale = 0.125f * 1.44269504f;  // 1/sqrt(64) * log2(e)
  dim3 gq(24, 64);  // 1536 blocks
  gemm_qkv<<<gq, 256, 0, stream>>>(xb, fb, wqkvt, bq, bk, bv, m01,
                                   Qb, Kb, Vtb, qscale);

  dim3 ga(16, 64);  // 1024 blocks
  attn_fwd8<<<ga, 256, 0, stream>>>(Qb, Kb, Vtb, m01, AO);

  dim3 go(8, 64);   // 512 blocks
  gemm_out<<<go, 256, 0, stream>>>(AO, wot, bo, out);
}

// Round 12
// 219.555 us; speedup vs baseline: 1.2418x; 1.0799x over previous
//
#include <hip/hip_runtime.h>
#include <stdint.h>
#include <type_traits>

typedef __attribute__((ext_vector_type(8))) short bf16x8;
typedef __attribute__((ext_vector_type(4))) float f32x4;
typedef __attribute__((ext_vector_type(16))) float f32x16;

#define BB 4
#define NH 16
#define TT 2048
#define HD 64
#define CC 1024

__device__ __forceinline__ unsigned short f2bf(float f) {
  unsigned int u = __builtin_bit_cast(unsigned int, f);
  u += 0x7fff + ((u >> 16) & 1);
  return (unsigned short)(u >> 16);
}

__device__ __forceinline__ float fast_exp2(float x) {
#if __has_builtin(__builtin_amdgcn_exp2f)
  return __builtin_amdgcn_exp2f(x);
#else
  return exp2f(x);
#endif
}

__device__ __forceinline__ unsigned int cvtpk(float lo, float hi) {
  unsigned int r;
  asm("v_cvt_pk_bf16_f32 %0, %1, %2" : "=v"(r) : "v"(lo), "v"(hi));
  return r;
}

__device__ __forceinline__ void plswap(unsigned int& a, unsigned int& b) {
#if __has_builtin(__builtin_amdgcn_permlane32_swap)
  auto r = __builtin_amdgcn_permlane32_swap(a, b, false, false);
  a = r[0];
  b = r[1];
#else
  unsigned int as = __shfl_xor((int)a, 32), bs = __shfl_xor((int)b, 32);
  bool hi = (threadIdx.x & 32) != 0;
  unsigned int na = hi ? bs : a;
  unsigned int nb = hi ? b : as;
  a = na; b = nb;
#endif
}

__device__ __forceinline__ float partner32(float x, bool hi) {
  unsigned int a = __builtin_bit_cast(unsigned int, x), b = a;
  plswap(a, b);
  return __builtin_bit_cast(float, hi ? a : b);
}

__device__ __forceinline__ void g2l16(const void* g, void* s) {
  __builtin_amdgcn_global_load_lds(
      (const __attribute__((address_space(1))) unsigned int*)g,
      (__attribute__((address_space(3))) unsigned int*)s, 16, 0, 0);
}

// ---------------- fused cast f32 -> bf16 (x and features) ----------------
__global__ __launch_bounds__(256) void cast2(
    const float* __restrict__ x, const float* __restrict__ ft,
    unsigned short* __restrict__ xb, unsigned short* __restrict__ fb, int n) {
  const float* in = blockIdx.y ? ft : x;
  unsigned short* out = blockIdx.y ? fb : xb;
  int i = (blockIdx.x * 256 + threadIdx.x) * 4;
  if (i >= n) return;
  float4 v = *(const float4*)(in + i);
  ushort4 o;
  o.x = f2bf(v.x); o.y = f2bf(v.y); o.z = f2bf(v.z); o.w = f2bf(v.w);
  *(ushort4*)(out + i) = o;
}

// ---------------- mask -> float 0/1 ----------------
__global__ __launch_bounds__(256) void make_m01(
    const int* __restrict__ mask, float* __restrict__ m01, int n) {
  int i = blockIdx.x * 256 + threadIdx.x;
  if (i < n) m01[i] = mask[i] ? 1.0f : 0.0f;
}

// -------- fused weight transpose+cast: 4 weights in one launch ------------
__global__ __launch_bounds__(256) void transpose_cast_w4(
    const float* __restrict__ wq, const float* __restrict__ wk,
    const float* __restrict__ wv, const float* __restrict__ wo,
    unsigned short* __restrict__ wqkvt, unsigned short* __restrict__ wot) {
  __shared__ float tile[32][33];
  const int z = blockIdx.z;
  const float* w = (z == 0) ? wq : (z == 1) ? wk : (z == 2) ? wv : wo;
  unsigned short* wt = (z < 3) ? wqkvt + (size_t)z * CC * CC : wot;
  int nb = blockIdx.x * 32, kb = blockIdx.y * 32;
  int tx = threadIdx.x, ty = threadIdx.y;
#pragma unroll
  for (int r = ty; r < 32; r += 8)
    tile[r][tx] = w[(size_t)(kb + r) * CC + nb + tx];
  __syncthreads();
#pragma unroll
  for (int r = ty; r < 32; r += 8)
    wt[(size_t)(nb + r) * CC + kb + tx] = f2bf(tile[tx][r]);
}

// ---------------- fused QKV GEMM: r8 form (BK=32, 16KB) + chunk swizzle ----
// [8192][1024] @ Wt[3072][1024]^T. Sections: 0->Qb (scaled), 1->Kb,
// 2->Vtb (B,H,D,T; masked rows zeroed, ushort4-packed stores).
// LDS rows are 64 B; 16-B chunk index XORed with (row&3) via pre-swizzled
// global source (linear g2l dest); read side applies the same XOR.
__global__ __launch_bounds__(256) void gemm_qkv(
    const unsigned short* __restrict__ xb, const unsigned short* __restrict__ fb,
    const unsigned short* __restrict__ Wt,
    const float* __restrict__ bq, const float* __restrict__ bk,
    const float* __restrict__ bv, const float* __restrict__ m01,
    unsigned short* __restrict__ Qb, unsigned short* __restrict__ Kb,
    unsigned short* __restrict__ Vtb, float qscale) {
  __shared__ unsigned short As[128 * 32];
  __shared__ unsigned short Bs[128 * 32];
  int lin = blockIdx.y * gridDim.x + blockIdx.x;
  int cpx = (gridDim.x * gridDim.y) >> 3;
  int sw = (lin & 7) * cpx + (lin >> 3);
  const int n0g = (sw % 24) * 128;
  const int m0 = (sw / 24) * 128;
  const int sec = n0g >> 10;
  const int n0 = n0g & (CC - 1);
  const unsigned short* A = (sec == 0) ? xb : fb;
  const unsigned short* Bt = Wt + (size_t)n0g * CC;

  const int t = threadIdx.x, l = t & 63, w = t >> 6;
  const int lr = l & 15, lg = l >> 4;
  const int wr = w >> 1, wc = w & 1;

  // staging: chunks c0=t, c1=t+256; row=c>>2, swizzled chunk=(c&3)^(row&3)
  const int c1 = t + 256;
  const int r0 = t >> 2, k0e = (((t & 3) ^ (r0 & 3)) * 8);
  const int r1 = c1 >> 2, k1e = (((c1 & 3) ^ (r1 & 3)) * 8);
  const unsigned short* gA0 = A + (size_t)(m0 + r0) * CC + k0e;
  const unsigned short* gA1 = A + (size_t)(m0 + r1) * CC + k1e;
  const unsigned short* gB0 = Bt + (size_t)r0 * CC + k0e;
  const unsigned short* gB1 = Bt + (size_t)r1 * CC + k1e;
  auto stage = [&]() {
    g2l16(gA0, (char*)As + t * 16);
    g2l16(gA1, (char*)As + t * 16 + 4096);
    g2l16(gB0, (char*)Bs + t * 16);
    g2l16(gB1, (char*)Bs + t * 16 + 4096);
    gA0 += 32; gA1 += 32; gB0 += 32; gB1 += 32;
  };

  // read offsets: row*64 + ((lg*16) ^ ((lr&3)<<4))
  const int colx = (lg * 16) ^ ((lr & 3) << 4);
  const int abase = (wr * 64 + lr) * 64 + colx;  // + mi*1024
  const int bbase = (wc * 64 + lr) * 64 + colx;  // + nj*1024

  f32x4 acc[4][4] = {};
  for (int j = 0; j < 32; ++j) {
    stage();
    asm volatile("s_waitcnt vmcnt(0)" ::: "memory");
    __syncthreads();
    bf16x8 af[4], bfr[4];
#pragma unroll
    for (int mi = 0; mi < 4; ++mi)
      af[mi] = *(const bf16x8*)((const char*)As + abase + mi * 1024);
#pragma unroll
    for (int nj = 0; nj < 4; ++nj)
      bfr[nj] = *(const bf16x8*)((const char*)Bs + bbase + nj * 1024);
#pragma unroll
    for (int mi = 0; mi < 4; ++mi)
#pragma unroll
      for (int nj = 0; nj < 4; ++nj)
        acc[mi][nj] = __builtin_amdgcn_mfma_f32_16x16x32_bf16(
            af[mi], bfr[nj], acc[mi][nj], 0, 0, 0);
    __syncthreads();
  }

  if (sec < 2) {
    const float* bp = (sec == 0) ? bq : bk;
    const float scale = (sec == 0) ? qscale : 1.0f;
    unsigned short* dst = (sec == 0) ? Qb : Kb;
#pragma unroll
    for (int mi = 0; mi < 4; ++mi) {
#pragma unroll
      for (int nj = 0; nj < 4; ++nj) {
        int col = n0 + wc * 64 + nj * 16 + lr;
        float bias = bp[col];
#pragma unroll
        for (int j = 0; j < 4; ++j) {
          int rowm = m0 + wr * 64 + mi * 16 + lg * 4 + j;
          float v = (acc[mi][nj][j] + bias) * scale;
          int b_ = rowm >> 11, tq = rowm & (TT - 1);
          int h_ = col >> 6, d_ = col & (HD - 1);
          dst[((size_t)((b_ * NH + h_) * TT + tq) << 6) + d_] = f2bf(v);
        }
      }
    }
  } else {
    // V^T: tq contiguous along j -> ushort4 stores; mask as float4
#pragma unroll
    for (int mi = 0; mi < 4; ++mi) {
      int rowb = m0 + wr * 64 + mi * 16 + lg * 4;
      int b_ = rowb >> 11, tq = rowb & (TT - 1);
      f32x4 mv = *(const f32x4*)(m01 + rowb);
#pragma unroll
      for (int nj = 0; nj < 4; ++nj) {
        int col = n0 + wc * 64 + nj * 16 + lr;
        float bias = bv[col];
        int h_ = col >> 6, d_ = col & (HD - 1);
        unsigned short pk[4];
#pragma unroll
        for (int j = 0; j < 4; ++j)
          pk[j] = f2bf((acc[mi][nj][j] + bias) * mv[j]);
        *(ushort4*)(Vtb + ((size_t)((b_ * NH + h_) * HD + d_) << 11) + tq) =
            *(ushort4*)pk;
      }
    }
  }
}

// ---------------- O-projection GEMM: BK=64, swizzled LDS (r11 form) --------
__global__ __launch_bounds__(256) void gemm_out(
    const unsigned short* __restrict__ A, const unsigned short* __restrict__ Bt,
    const float* __restrict__ bias, float* __restrict__ Out) {
  __shared__ unsigned short As[128 * 64];
  __shared__ unsigned short Bs[128 * 64];
  int lin = blockIdx.y * gridDim.x + blockIdx.x;
  int cpx = (gridDim.x * gridDim.y) >> 3;
  int sw = (lin & 7) * cpx + (lin >> 3);
  const int n0 = (sw % 8) * 128;
  const int m0 = (sw / 8) * 128;
  const int t = threadIdx.x, l = t & 63, w = t >> 6;
  const int lr = l & 15, lg = l >> 4;
  const int wr = w >> 1, wc = w & 1;

  const int sR = t >> 3;
  const int sx = ((t & 7) * 16) ^ ((sR & 7) << 4);
  const unsigned short* gA = A + (size_t)(m0 + sR) * CC + (sx >> 1);
  const unsigned short* gB = Bt + (size_t)(n0 + sR) * CC + (sx >> 1);
  auto stage = [&]() {
#pragma unroll
    for (int i = 0; i < 4; ++i) {
      g2l16(gA + (size_t)(i * 32) * CC, (char*)As + t * 16 + i * 4096);
      g2l16(gB + (size_t)(i * 32) * CC, (char*)Bs + t * 16 + i * 4096);
    }
    gA += 64; gB += 64;
  };

  const int axs = (lr & 7) << 4;
  const int col0 = (lg * 16) ^ axs;
  const int col1 = (64 + lg * 16) ^ axs;
  const int abase = (wr * 64 + lr) * 128;
  const int bbase = (wc * 64 + lr) * 128;

  f32x4 acc[4][4] = {};
  for (int j = 0; j < 16; ++j) {
    stage();
    asm volatile("s_waitcnt vmcnt(0)" ::: "memory");
    __syncthreads();
    bf16x8 af[4], bfr[4];
#pragma unroll
    for (int mi = 0; mi < 4; ++mi)
      af[mi] = *(const bf16x8*)((const char*)As + abase + mi * 2048 + col0);
#pragma unroll
    for (int nj = 0; nj < 4; ++nj)
      bfr[nj] = *(const bf16x8*)((const char*)Bs + bbase + nj * 2048 + col0);
#pragma unroll
    for (int mi = 0; mi < 4; ++mi)
#pragma unroll
      for (int nj = 0; nj < 4; ++nj)
        acc[mi][nj] = __builtin_amdgcn_mfma_f32_16x16x32_bf16(
            af[mi], bfr[nj], acc[mi][nj], 0, 0, 0);
#pragma unroll
    for (int mi = 0; mi < 4; ++mi)
      af[mi] = *(const bf16x8*)((const char*)As + abase + mi * 2048 + col1);
#pragma unroll
    for (int nj = 0; nj < 4; ++nj)
      bfr[nj] = *(const bf16x8*)((const char*)Bs + bbase + nj * 2048 + col1);
#pragma unroll
    for (int mi = 0; mi < 4; ++mi)
#pragma unroll
      for (int nj = 0; nj < 4; ++nj)
        acc[mi][nj] = __builtin_amdgcn_mfma_f32_16x16x32_bf16(
            af[mi], bfr[nj], acc[mi][nj], 0, 0, 0);
    __syncthreads();
  }

#pragma unroll
  for (int mi = 0; mi < 4; ++mi) {
#pragma unroll
    for (int nj = 0; nj < 4; ++nj) {
      int col = n0 + wc * 64 + nj * 16 + lr;
      float bv = bias[col];
#pragma unroll
      for (int j = 0; j < 4; ++j) {
        int rowm = m0 + wr * 64 + mi * 16 + lg * 4 + j;
        Out[(size_t)rowm * CC + col] = acc[mi][nj][j] + bv;
      }
    }
  }
}

// ---------------- flash attention v8: scale-free softmax (unchanged) -------
__global__ __launch_bounds__(256) void attn_fwd8(
    const unsigned short* __restrict__ Q, const unsigned short* __restrict__ K,
    const unsigned short* __restrict__ Vt, const float* __restrict__ m01,
    unsigned short* __restrict__ O) {
  __shared__ __attribute__((aligned(64))) char ldsb[40960];
  const int t = threadIdx.x, l = t & 63, w = t >> 6;
  const int q5 = l & 31, hig = l >> 5;
  const bool hib = hig != 0;
  int lin = blockIdx.y * gridDim.x + blockIdx.x;
  int sw = (lin & 7) * 128 + (lin >> 3);
  const int bx = sw & 15, bh = sw >> 4;
  const int b_ = bh >> 4, h_ = bh & (NH - 1);
  const int q = bx * 128 + w * 32 + q5;
  const size_t base = (size_t)bh * TT * HD;
  const unsigned short* Kg = K + base;
  const unsigned short* Vg = Vt + (size_t)bh * HD * TT;

  bf16x8 qf[4];
  {
    const unsigned short* qp = Q + base + (size_t)q * HD + 8 * hig;
#pragma unroll
    for (int dk = 0; dk < 4; ++dk) qf[dk] = *(const bf16x8*)(qp + dk * 16);
  }

  int ka[4];
  {
    int swz = (q5 & 7) << 4;
#pragma unroll
    for (int dk = 0; dk < 4; ++dk)
      ka[dk] = q5 * 128 + ((dk * 32 + hig * 16) ^ swz);
  }
  int moff = 32768 + hig * 16;

  const int s1 = t + 256;
  const int r0 = t >> 3, c0 = (t & 7) * 16, x0 = c0 ^ ((r0 & 7) << 4);
  const int r1 = s1 >> 3, c1 = (s1 & 7) * 16, x1 = c1 ^ ((r1 & 7) << 4);
  const unsigned short* gk0 = Kg + r0 * HD + (x0 >> 1);
  const unsigned short* gk1 = Kg + r1 * HD + (x1 >> 1);
  const unsigned short* gv0 = Vg + (size_t)r0 * TT + (x0 >> 1);
  const unsigned short* gv1 = Vg + (size_t)r1 * TT + (x1 >> 1);

  auto stage = [&](int boff) {
    g2l16(gk0, ldsb + t * 16 + boff);
    g2l16(gk1, ldsb + t * 16 + 4096 + boff);
    g2l16(gv0, ldsb + 16384 + t * 16 + boff);
    g2l16(gv1, ldsb + 16384 + t * 16 + 4096 + boff);
    gk0 += 4096; gk1 += 4096; gv0 += 64; gv1 += 64;
  };

  f32x16 ot[2];
#pragma unroll
  for (int i = 0; i < 16; ++i) { ot[0][i] = 0.f; ot[1][i] = 0.f; }
  float l0 = 0.f, l1 = 0.f, l2 = 0.f, l3 = 0.f;

  {
    const float* mg = m01 + (size_t)b_ * TT;
#pragma unroll
    for (int i = 0; i < 2; ++i) {
      int s = t + i * 256;
      g2l16(mg + s * 4, ldsb + 32768 + s * 16);
    }
  }
  stage(0);
  asm volatile("s_waitcnt vmcnt(0)" ::: "memory");
  __syncthreads();

  auto compute = [&](auto Bc) {
    constexpr int BO = decltype(Bc)::value;
    constexpr int MO = BO ? 256 : 0;
    f32x16 s[2] = {};
    __builtin_amdgcn_s_setprio(1);
#pragma unroll
    for (int dk = 0; dk < 4; ++dk) {
      bf16x8 kf0 = *(const bf16x8*)(ldsb + ka[dk] + BO);
      bf16x8 kf1 = *(const bf16x8*)(ldsb + ka[dk] + 4096 + BO);
      s[0] = __builtin_amdgcn_mfma_f32_32x32x16_bf16(kf0, qf[dk], s[0], 0, 0, 0);
      s[1] = __builtin_amdgcn_mfma_f32_32x32x16_bf16(kf1, qf[dk], s[1], 0, 0, 0);
    }
    __builtin_amdgcn_s_setprio(0);

    unsigned int wl[2][4], wh[2][4];
#pragma unroll
    for (int kk = 0; kk < 2; ++kk)
#pragma unroll
      for (int g = 0; g < 4; ++g) {
        int i = g * 4;
        float e0 = fast_exp2(s[kk][i + 0]);
        float e1 = fast_exp2(s[kk][i + 1]);
        float e2 = fast_exp2(s[kk][i + 2]);
        float e3 = fast_exp2(s[kk][i + 3]);
        f32x4 mk = *(const f32x4*)(ldsb + moff + MO + kk * 128 + g * 32);
        l0 = fmaf(e0, mk[0], l0);
        l1 = fmaf(e1, mk[1], l1);
        l2 = fmaf(e2, mk[2], l2);
        l3 = fmaf(e3, mk[3], l3);
        wl[kk][g] = cvtpk(e0, e1);
        wh[kk][g] = cvtpk(e2, e3);
      }

    bf16x8 pa[4];
#pragma unroll
    for (int ks = 0; ks < 4; ++ks) {
      const int kk = ks >> 1, gA = 2 * (ks & 1), gB = gA + 1;
      unsigned int a0 = wl[kk][gA], b0 = wl[kk][gB];
      unsigned int a1 = wh[kk][gA], b1 = wh[kk][gB];
      plswap(a0, b0);
      plswap(a1, b1);
      unsigned int pw[4] = {a0, a1, b0, b1};
      pa[ks] = *(bf16x8*)pw;
    }

    __builtin_amdgcn_s_setprio(1);
#pragma unroll
    for (int ks = 0; ks < 4; ++ks) {
      bf16x8 vf0 = *(const bf16x8*)(ldsb + ka[ks] + 16384 + BO);
      bf16x8 vf1 = *(const bf16x8*)(ldsb + ka[ks] + 16384 + 4096 + BO);
      ot[0] = __builtin_amdgcn_mfma_f32_32x32x16_bf16(vf0, pa[ks], ot[0], 0, 0, 0);
      ot[1] = __builtin_amdgcn_mfma_f32_32x32x16_bf16(vf1, pa[ks], ot[1], 0, 0, 0);
    }
    __builtin_amdgcn_s_setprio(0);
  };

  for (int j = 0; j < 16; ++j) {
    stage(8192);
    compute(std::integral_constant<int, 0>{});
    asm volatile("s_waitcnt vmcnt(0)" ::: "memory");
    __syncthreads();
    if (j < 15) stage(0);
    compute(std::integral_constant<int, 8192>{});
    asm volatile("s_waitcnt vmcnt(0)" ::: "memory");
    __syncthreads();
    moff += 512;
  }

  float l_ = (l0 + l1) + (l2 + l3);
  float l_tot = l_ + partner32(l_, hib);
  const float inv = 1.f / l_tot;
  unsigned short* orow = O + ((size_t)(b_ * TT) + q) * CC + h_ * 64 + 4 * hig;
#pragma unroll
  for (int dt = 0; dt < 2; ++dt)
#pragma unroll
    for (int g = 0; g < 4; ++g) {
      unsigned short pk4[4];
#pragma unroll
      for (int j = 0; j < 4; ++j) pk4[j] = f2bf(ot[dt][4 * g + j] * inv);
      *(ushort4*)(orow + dt * 32 + 8 * g) = *(ushort4*)pk4;
    }
}

extern "C" void kernel_launch(void* const* d_in, const int* in_sizes, int n_in,
                              void* d_out, int out_size, void* d_ws, size_t ws_size,
                              hipStream_t stream) {
  const float* x  = (const float*)d_in[0];
  const float* ft = (const float*)d_in[1];
  const int* mask = (const int*)d_in[2];
  const float* wq = (const float*)d_in[3];
  const float* bq = (const float*)d_in[4];
  const float* wk = (const float*)d_in[5];
  const float* bk = (const float*)d_in[6];
  const float* wv = (const float*)d_in[7];
  const float* bv = (const float*)d_in[8];
  const float* wo = (const float*)d_in[9];
  const float* bo = (const float*)d_in[10];
  float* out = (float*)d_out;

  char* ws = (char*)d_ws;
  const size_t NTOK = (size_t)BB * TT;   // 8192
  const size_t SB = NTOK * CC * 2;       // 16 MiB
  unsigned short* xb   = (unsigned short*)ws; ws += SB;
  unsigned short* fb   = (unsigned short*)ws; ws += SB;
  unsigned short* Qb   = (unsigned short*)ws; ws += SB;
  unsigned short* Kb   = (unsigned short*)ws; ws += SB;
  unsigned short* Vtb  = (unsigned short*)ws; ws += SB;   // V^T (b,h,d,t)
  unsigned short* AO   = (unsigned short*)ws; ws += SB;
  unsigned short* wqkvt = (unsigned short*)ws; ws += (size_t)3 * CC * CC * 2;
  unsigned short* wot   = (unsigned short*)ws; ws += (size_t)CC * CC * 2;
  float* m01 = (float*)ws; ws += NTOK * 4;

  int ncast = (int)(NTOK * CC);
  dim3 gc(ncast / 4 / 256, 2);
  cast2<<<gc, 256, 0, stream>>>(x, ft, xb, fb, ncast);
  dim3 tb(32, 8), tg(32, 32, 4);
  transpose_cast_w4<<<tg, tb, 0, stream>>>(wq, wk, wv, wo, wqkvt, wot);
  make_m01<<<(int)(NTOK / 256), 256, 0, stream>>>(mask, m01, (int)NTOK);

  const float qscale = 0.125f * 1.44269504f;  // 1/sqrt(64) * log2(e)
  dim3 gq(24, 64);  // 1536 blocks
  gemm_qkv<<<gq, 256, 0, stream>>>(xb, fb, wqkvt, bq, bk, bv, m01,
                                   Qb, Kb, Vtb, qscale);

  dim3 ga(16, 64);  // 1024 blocks
  attn_fwd8<<<ga, 256, 0, stream>>>(Qb, Kb, Vtb, m01, AO);

  dim3 go(8, 64);   // 512 blocks
  gemm_out<<<go, 256, 0, stream>>>(AO, wot, bo, out);
}

// Round 13
// 218.962 us; speedup vs baseline: 1.2452x; 1.0027x over previous
//
#include <hip/hip_runtime.h>
#include <stdint.h>
#include <type_traits>

typedef __attribute__((ext_vector_type(8))) short bf16x8;
typedef __attribute__((ext_vector_type(4))) float f32x4;
typedef __attribute__((ext_vector_type(16))) float f32x16;

#define BB 4
#define NH 16
#define TT 2048
#define HD 64
#define CC 1024

__device__ __forceinline__ unsigned short f2bf(float f) {
  unsigned int u = __builtin_bit_cast(unsigned int, f);
  u += 0x7fff + ((u >> 16) & 1);
  return (unsigned short)(u >> 16);
}

__device__ __forceinline__ float fast_exp2(float x) {
#if __has_builtin(__builtin_amdgcn_exp2f)
  return __builtin_amdgcn_exp2f(x);
#else
  return exp2f(x);
#endif
}

__device__ __forceinline__ unsigned int cvtpk(float lo, float hi) {
  unsigned int r;
  asm("v_cvt_pk_bf16_f32 %0, %1, %2" : "=v"(r) : "v"(lo), "v"(hi));
  return r;
}

__device__ __forceinline__ void plswap(unsigned int& a, unsigned int& b) {
#if __has_builtin(__builtin_amdgcn_permlane32_swap)
  auto r = __builtin_amdgcn_permlane32_swap(a, b, false, false);
  a = r[0];
  b = r[1];
#else
  unsigned int as = __shfl_xor((int)a, 32), bs = __shfl_xor((int)b, 32);
  bool hi = (threadIdx.x & 32) != 0;
  unsigned int na = hi ? bs : a;
  unsigned int nb = hi ? b : as;
  a = na; b = nb;
#endif
}

__device__ __forceinline__ float partner32(float x, bool hi) {
  unsigned int a = __builtin_bit_cast(unsigned int, x), b = a;
  plswap(a, b);
  return __builtin_bit_cast(float, hi ? a : b);
}

__device__ __forceinline__ void g2l16(const void* g, void* s) {
  __builtin_amdgcn_global_load_lds(
      (const __attribute__((address_space(1))) unsigned int*)g,
      (__attribute__((address_space(3))) unsigned int*)s, 16, 0, 0);
}

// ---------------- fused cast f32 -> bf16 (x and features) ----------------
__global__ __launch_bounds__(256) void cast2(
    const float* __restrict__ x, const float* __restrict__ ft,
    unsigned short* __restrict__ xb, unsigned short* __restrict__ fb, int n) {
  const float* in = blockIdx.y ? ft : x;
  unsigned short* out = blockIdx.y ? fb : xb;
  int i = (blockIdx.x * 256 + threadIdx.x) * 4;
  if (i >= n) return;
  float4 v = *(const float4*)(in + i);
  ushort4 o;
  o.x = f2bf(v.x); o.y = f2bf(v.y); o.z = f2bf(v.z); o.w = f2bf(v.w);
  *(ushort4*)(out + i) = o;
}

// ---------------- mask -> float 0/1 ----------------
__global__ __launch_bounds__(256) void make_m01(
    const int* __restrict__ mask, float* __restrict__ m01, int n) {
  int i = blockIdx.x * 256 + threadIdx.x;
  if (i < n) m01[i] = mask[i] ? 1.0f : 0.0f;
}

// -------- fused weight transpose+cast: 4 weights in one launch ------------
__global__ __launch_bounds__(256) void transpose_cast_w4(
    const float* __restrict__ wq, const float* __restrict__ wk,
    const float* __restrict__ wv, const float* __restrict__ wo,
    unsigned short* __restrict__ wqkvt, unsigned short* __restrict__ wot) {
  __shared__ float tile[32][33];
  const int z = blockIdx.z;
  const float* w = (z == 0) ? wq : (z == 1) ? wk : (z == 2) ? wv : wo;
  unsigned short* wt = (z < 3) ? wqkvt + (size_t)z * CC * CC : wot;
  int nb = blockIdx.x * 32, kb = blockIdx.y * 32;
  int tx = threadIdx.x, ty = threadIdx.y;
#pragma unroll
  for (int r = ty; r < 32; r += 8)
    tile[r][tx] = w[(size_t)(kb + r) * CC + nb + tx];
  __syncthreads();
#pragma unroll
  for (int r = ty; r < 32; r += 8)
    wt[(size_t)(nb + r) * CC + kb + tx] = f2bf(tile[tx][r]);
}

// ---------------- fused QKV GEMM: r12 form (BK=32, 16KB, chunk swizzle) ----
__global__ __launch_bounds__(256) void gemm_qkv(
    const unsigned short* __restrict__ xb, const unsigned short* __restrict__ fb,
    const unsigned short* __restrict__ Wt,
    const float* __restrict__ bq, const float* __restrict__ bk,
    const float* __restrict__ bv, const float* __restrict__ m01,
    unsigned short* __restrict__ Qb, unsigned short* __restrict__ Kb,
    unsigned short* __restrict__ Vtb, float qscale) {
  __shared__ unsigned short As[128 * 32];
  __shared__ unsigned short Bs[128 * 32];
  int lin = blockIdx.y * gridDim.x + blockIdx.x;
  int cpx = (gridDim.x * gridDim.y) >> 3;
  int sw = (lin & 7) * cpx + (lin >> 3);
  const int n0g = (sw % 24) * 128;
  const int m0 = (sw / 24) * 128;
  const int sec = n0g >> 10;
  const int n0 = n0g & (CC - 1);
  const unsigned short* A = (sec == 0) ? xb : fb;
  const unsigned short* Bt = Wt + (size_t)n0g * CC;

  const int t = threadIdx.x, l = t & 63, w = t >> 6;
  const int lr = l & 15, lg = l >> 4;
  const int wr = w >> 1, wc = w & 1;

  const int c1 = t + 256;
  const int r0 = t >> 2, k0e = (((t & 3) ^ (r0 & 3)) * 8);
  const int r1 = c1 >> 2, k1e = (((c1 & 3) ^ (r1 & 3)) * 8);
  const unsigned short* gA0 = A + (size_t)(m0 + r0) * CC + k0e;
  const unsigned short* gA1 = A + (size_t)(m0 + r1) * CC + k1e;
  const unsigned short* gB0 = Bt + (size_t)r0 * CC + k0e;
  const unsigned short* gB1 = Bt + (size_t)r1 * CC + k1e;
  auto stage = [&]() {
    g2l16(gA0, (char*)As + t * 16);
    g2l16(gA1, (char*)As + t * 16 + 4096);
    g2l16(gB0, (char*)Bs + t * 16);
    g2l16(gB1, (char*)Bs + t * 16 + 4096);
    gA0 += 32; gA1 += 32; gB0 += 32; gB1 += 32;
  };

  const int colx = (lg * 16) ^ ((lr & 3) << 4);
  const int abase = (wr * 64 + lr) * 64 + colx;
  const int bbase = (wc * 64 + lr) * 64 + colx;

  f32x4 acc[4][4] = {};
  for (int j = 0; j < 32; ++j) {
    stage();
    asm volatile("s_waitcnt vmcnt(0)" ::: "memory");
    __syncthreads();
    bf16x8 af[4], bfr[4];
#pragma unroll
    for (int mi = 0; mi < 4; ++mi)
      af[mi] = *(const bf16x8*)((const char*)As + abase + mi * 1024);
#pragma unroll
    for (int nj = 0; nj < 4; ++nj)
      bfr[nj] = *(const bf16x8*)((const char*)Bs + bbase + nj * 1024);
#pragma unroll
    for (int mi = 0; mi < 4; ++mi)
#pragma unroll
      for (int nj = 0; nj < 4; ++nj)
        acc[mi][nj] = __builtin_amdgcn_mfma_f32_16x16x32_bf16(
            af[mi], bfr[nj], acc[mi][nj], 0, 0, 0);
    __syncthreads();
  }

  if (sec < 2) {
    const float* bp = (sec == 0) ? bq : bk;
    const float scale = (sec == 0) ? qscale : 1.0f;
    unsigned short* dst = (sec == 0) ? Qb : Kb;
#pragma unroll
    for (int mi = 0; mi < 4; ++mi) {
#pragma unroll
      for (int nj = 0; nj < 4; ++nj) {
        int col = n0 + wc * 64 + nj * 16 + lr;
        float bias = bp[col];
#pragma unroll
        for (int j = 0; j < 4; ++j) {
          int rowm = m0 + wr * 64 + mi * 16 + lg * 4 + j;
          float v = (acc[mi][nj][j] + bias) * scale;
          int b_ = rowm >> 11, tq = rowm & (TT - 1);
          int h_ = col >> 6, d_ = col & (HD - 1);
          dst[((size_t)((b_ * NH + h_) * TT + tq) << 6) + d_] = f2bf(v);
        }
      }
    }
  } else {
#pragma unroll
    for (int mi = 0; mi < 4; ++mi) {
      int rowb = m0 + wr * 64 + mi * 16 + lg * 4;
      int b_ = rowb >> 11, tq = rowb & (TT - 1);
      f32x4 mv = *(const f32x4*)(m01 + rowb);
#pragma unroll
      for (int nj = 0; nj < 4; ++nj) {
        int col = n0 + wc * 64 + nj * 16 + lr;
        float bias = bv[col];
        int h_ = col >> 6, d_ = col & (HD - 1);
        unsigned short pk[4];
#pragma unroll
        for (int j = 0; j < 4; ++j)
          pk[j] = f2bf((acc[mi][nj][j] + bias) * mv[j]);
        *(ushort4*)(Vtb + ((size_t)((b_ * NH + h_) * HD + d_) << 11) + tq) =
            *(ushort4*)pk;
      }
    }
  }
}

// ---------------- O-projection GEMM: BK=64, swizzled LDS (r11 form) --------
__global__ __launch_bounds__(256) void gemm_out(
    const unsigned short* __restrict__ A, const unsigned short* __restrict__ Bt,
    const float* __restrict__ bias, float* __restrict__ Out) {
  __shared__ unsigned short As[128 * 64];
  __shared__ unsigned short Bs[128 * 64];
  int lin = blockIdx.y * gridDim.x + blockIdx.x;
  int cpx = (gridDim.x * gridDim.y) >> 3;
  int sw = (lin & 7) * cpx + (lin >> 3);
  const int n0 = (sw % 8) * 128;
  const int m0 = (sw / 8) * 128;
  const int t = threadIdx.x, l = t & 63, w = t >> 6;
  const int lr = l & 15, lg = l >> 4;
  const int wr = w >> 1, wc = w & 1;

  const int sR = t >> 3;
  const int sx = ((t & 7) * 16) ^ ((sR & 7) << 4);
  const unsigned short* gA = A + (size_t)(m0 + sR) * CC + (sx >> 1);
  const unsigned short* gB = Bt + (size_t)(n0 + sR) * CC + (sx >> 1);
  auto stage = [&]() {
#pragma unroll
    for (int i = 0; i < 4; ++i) {
      g2l16(gA + (size_t)(i * 32) * CC, (char*)As + t * 16 + i * 4096);
      g2l16(gB + (size_t)(i * 32) * CC, (char*)Bs + t * 16 + i * 4096);
    }
    gA += 64; gB += 64;
  };

  const int axs = (lr & 7) << 4;
  const int col0 = (lg * 16) ^ axs;
  const int col1 = (64 + lg * 16) ^ axs;
  const int abase = (wr * 64 + lr) * 128;
  const int bbase = (wc * 64 + lr) * 128;

  f32x4 acc[4][4] = {};
  for (int j = 0; j < 16; ++j) {
    stage();
    asm volatile("s_waitcnt vmcnt(0)" ::: "memory");
    __syncthreads();
    bf16x8 af[4], bfr[4];
#pragma unroll
    for (int mi = 0; mi < 4; ++mi)
      af[mi] = *(const bf16x8*)((const char*)As + abase + mi * 2048 + col0);
#pragma unroll
    for (int nj = 0; nj < 4; ++nj)
      bfr[nj] = *(const bf16x8*)((const char*)Bs + bbase + nj * 2048 + col0);
#pragma unroll
    for (int mi = 0; mi < 4; ++mi)
#pragma unroll
      for (int nj = 0; nj < 4; ++nj)
        acc[mi][nj] = __builtin_amdgcn_mfma_f32_16x16x32_bf16(
            af[mi], bfr[nj], acc[mi][nj], 0, 0, 0);
#pragma unroll
    for (int mi = 0; mi < 4; ++mi)
      af[mi] = *(const bf16x8*)((const char*)As + abase + mi * 2048 + col1);
#pragma unroll
    for (int nj = 0; nj < 4; ++nj)
      bfr[nj] = *(const bf16x8*)((const char*)Bs + bbase + nj * 2048 + col1);
#pragma unroll
    for (int mi = 0; mi < 4; ++mi)
#pragma unroll
      for (int nj = 0; nj < 4; ++nj)
        acc[mi][nj] = __builtin_amdgcn_mfma_f32_16x16x32_bf16(
            af[mi], bfr[nj], acc[mi][nj], 0, 0, 0);
    __syncthreads();
  }

#pragma unroll
  for (int mi = 0; mi < 4; ++mi) {
#pragma unroll
    for (int nj = 0; nj < 4; ++nj) {
      int col = n0 + wc * 64 + nj * 16 + lr;
      float bv = bias[col];
#pragma unroll
      for (int j = 0; j < 4; ++j) {
        int rowm = m0 + wr * 64 + mi * 16 + lg * 4 + j;
        Out[(size_t)rowm * CC + col] = acc[mi][nj][j] + bv;
      }
    }
  }
}

// ---------------- flash attention v9: kk-split for register pressure -------
// Per tile, each kk-half is processed end-to-end (QK -> exp -> pa -> PV),
// halving live S/cvtpk/pa ranges (target: unified regs <= 128 -> 4 w/SIMD).
__global__ __launch_bounds__(256) void attn_fwd9(
    const unsigned short* __restrict__ Q, const unsigned short* __restrict__ K,
    const unsigned short* __restrict__ Vt, const float* __restrict__ m01,
    unsigned short* __restrict__ O) {
  __shared__ __attribute__((aligned(64))) char ldsb[40960];
  const int t = threadIdx.x, l = t & 63, w = t >> 6;
  const int q5 = l & 31, hig = l >> 5;
  const bool hib = hig != 0;
  int lin = blockIdx.y * gridDim.x + blockIdx.x;
  int sw = (lin & 7) * 128 + (lin >> 3);
  const int bx = sw & 15, bh = sw >> 4;
  const int b_ = bh >> 4, h_ = bh & (NH - 1);
  const int q = bx * 128 + w * 32 + q5;
  const size_t base = (size_t)bh * TT * HD;
  const unsigned short* Kg = K + base;
  const unsigned short* Vg = Vt + (size_t)bh * HD * TT;

  bf16x8 qf[4];
  {
    const unsigned short* qp = Q + base + (size_t)q * HD + 8 * hig;
#pragma unroll
    for (int dk = 0; dk < 4; ++dk) qf[dk] = *(const bf16x8*)(qp + dk * 16);
  }

  int ka[4];
  {
    int swz = (q5 & 7) << 4;
#pragma unroll
    for (int dk = 0; dk < 4; ++dk)
      ka[dk] = q5 * 128 + ((dk * 32 + hig * 16) ^ swz);
  }
  int moff = 32768 + hig * 16;

  const int s1 = t + 256;
  const int r0 = t >> 3, c0 = (t & 7) * 16, x0 = c0 ^ ((r0 & 7) << 4);
  const int r1 = s1 >> 3, c1 = (s1 & 7) * 16, x1 = c1 ^ ((r1 & 7) << 4);
  const unsigned short* gk0 = Kg + r0 * HD + (x0 >> 1);
  const unsigned short* gk1 = Kg + r1 * HD + (x1 >> 1);
  const unsigned short* gv0 = Vg + (size_t)r0 * TT + (x0 >> 1);
  const unsigned short* gv1 = Vg + (size_t)r1 * TT + (x1 >> 1);

  auto stage = [&](int boff) {
    g2l16(gk0, ldsb + t * 16 + boff);
    g2l16(gk1, ldsb + t * 16 + 4096 + boff);
    g2l16(gv0, ldsb + 16384 + t * 16 + boff);
    g2l16(gv1, ldsb + 16384 + t * 16 + 4096 + boff);
    gk0 += 4096; gk1 += 4096; gv0 += 64; gv1 += 64;
  };

  f32x16 ot[2];
#pragma unroll
  for (int i = 0; i < 16; ++i) { ot[0][i] = 0.f; ot[1][i] = 0.f; }
  float l0 = 0.f, l1 = 0.f, l2 = 0.f, l3 = 0.f;

  {
    const float* mg = m01 + (size_t)b_ * TT;
#pragma unroll
    for (int i = 0; i < 2; ++i) {
      int s = t + i * 256;
      g2l16(mg + s * 4, ldsb + 32768 + s * 16);
    }
  }
  stage(0);
  asm volatile("s_waitcnt vmcnt(0)" ::: "memory");
  __syncthreads();

  auto compute = [&](auto Bc) {
    constexpr int BO = decltype(Bc)::value;     // 0 or 8192 (buffer)
    constexpr int MO = BO ? 256 : 0;            // mask sub-offset
#pragma unroll
    for (int kk = 0; kk < 2; ++kk) {
      // S-half = K(kk) @ Q^T
      f32x16 s = {};
      __builtin_amdgcn_s_setprio(1);
#pragma unroll
      for (int dk = 0; dk < 4; ++dk) {
        bf16x8 kf = *(const bf16x8*)(ldsb + ka[dk] + kk * 4096 + BO);
        s = __builtin_amdgcn_mfma_f32_32x32x16_bf16(kf, qf[dk], s, 0, 0, 0);
      }
      __builtin_amdgcn_s_setprio(0);

      // p = exp2(s); denominator via fmac with 0/1 mask; pack to bf16
      unsigned int wl[4], wh[4];
#pragma unroll
      for (int g = 0; g < 4; ++g) {
        int i = g * 4;
        float e0 = fast_exp2(s[i + 0]);
        float e1 = fast_exp2(s[i + 1]);
        float e2 = fast_exp2(s[i + 2]);
        float e3 = fast_exp2(s[i + 3]);
        f32x4 mk = *(const f32x4*)(ldsb + moff + MO + kk * 128 + g * 32);
        l0 = fmaf(e0, mk[0], l0);
        l1 = fmaf(e1, mk[1], l1);
        l2 = fmaf(e2, mk[2], l2);
        l3 = fmaf(e3, mk[3], l3);
        wl[g] = cvtpk(e0, e1);
        wh[g] = cvtpk(e2, e3);
      }

      // pa fragments for this kk-half (ks = kk*2 + {0,1})
      bf16x8 pa[2];
#pragma unroll
      for (int kh = 0; kh < 2; ++kh) {
        const int gA = 2 * kh, gB = gA + 1;
        unsigned int a0 = wl[gA], b0 = wl[gB];
        unsigned int a1 = wh[gA], b1 = wh[gB];
        plswap(a0, b0);
        plswap(a1, b1);
        unsigned int pw[4] = {a0, a1, b0, b1};
        pa[kh] = *(bf16x8*)pw;
      }

      // O^T += V^T(ks) @ P^T(ks) for the two ks of this half
      __builtin_amdgcn_s_setprio(1);
#pragma unroll
      for (int kh = 0; kh < 2; ++kh) {
        const int ks = kk * 2 + kh;
        bf16x8 vf0 = *(const bf16x8*)(ldsb + ka[ks] + 16384 + BO);
        bf16x8 vf1 = *(const bf16x8*)(ldsb + ka[ks] + 16384 + 4096 + BO);
        ot[0] = __builtin_amdgcn_mfma_f32_32x32x16_bf16(vf0, pa[kh], ot[0], 0, 0, 0);
        ot[1] = __builtin_amdgcn_mfma_f32_32x32x16_bf16(vf1, pa[kh], ot[1], 0, 0, 0);
      }
      __builtin_amdgcn_s_setprio(0);
    }
  };

  for (int j = 0; j < 16; ++j) {
    stage(8192);
    compute(std::integral_constant<int, 0>{});
    asm volatile("s_waitcnt vmcnt(0)" ::: "memory");
    __syncthreads();
    if (j < 15) stage(0);
    compute(std::integral_constant<int, 8192>{});
    asm volatile("s_waitcnt vmcnt(0)" ::: "memory");
    __syncthreads();
    moff += 512;
  }

  float l_ = (l0 + l1) + (l2 + l3);
  float l_tot = l_ + partner32(l_, hib);
  const float inv = 1.f / l_tot;
  unsigned short* orow = O + ((size_t)(b_ * TT) + q) * CC + h_ * 64 + 4 * hig;
#pragma unroll
  for (int dt = 0; dt < 2; ++dt)
#pragma unroll
    for (int g = 0; g < 4; ++g) {
      unsigned short pk4[4];
#pragma unroll
      for (int j = 0; j < 4; ++j) pk4[j] = f2bf(ot[dt][4 * g + j] * inv);
      *(ushort4*)(orow + dt * 32 + 8 * g) = *(ushort4*)pk4;
    }
}

extern "C" void kernel_launch(void* const* d_in, const int* in_sizes, int n_in,
                              void* d_out, int out_size, void* d_ws, size_t ws_size,
                              hipStream_t stream) {
  const float* x  = (const float*)d_in[0];
  const float* ft = (const float*)d_in[1];
  const int* mask = (const int*)d_in[2];
  const float* wq = (const float*)d_in[3];
  const float* bq = (const float*)d_in[4];
  const float* wk = (const float*)d_in[5];
  const float* bk = (const float*)d_in[6];
  const float* wv = (const float*)d_in[7];
  const float* bv = (const float*)d_in[8];
  const float* wo = (const float*)d_in[9];
  const float* bo = (const float*)d_in[10];
  float* out = (float*)d_out;

  char* ws = (char*)d_ws;
  const size_t NTOK = (size_t)BB * TT;   // 8192
  const size_t SB = NTOK * CC * 2;       // 16 MiB
  unsigned short* xb   = (unsigned short*)ws; ws += SB;
  unsigned short* fb   = (unsigned short*)ws; ws += SB;
  unsigned short* Qb   = (unsigned short*)ws; ws += SB;
  unsigned short* Kb   = (unsigned short*)ws; ws += SB;
  unsigned short* Vtb  = (unsigned short*)ws; ws += SB;   // V^T (b,h,d,t)
  unsigned short* AO   = (unsigned short*)ws; ws += SB;
  unsigned short* wqkvt = (unsigned short*)ws; ws += (size_t)3 * CC * CC * 2;
  unsigned short* wot   = (unsigned short*)ws; ws += (size_t)CC * CC * 2;
  float* m01 = (float*)ws; ws += NTOK * 4;

  int ncast = (int)(NTOK * CC);
  dim3 gc(ncast / 4 / 256, 2);
  cast2<<<gc, 256, 0, stream>>>(x, ft, xb, fb, ncast);
  dim3 tb(32, 8), tg(32, 32, 4);
  transpose_cast_w4<<<tg, tb, 0, stream>>>(wq, wk, wv, wo, wqkvt, wot);
  make_m01<<<(int)(NTOK / 256), 256, 0, stream>>>(mask, m01, (int)NTOK);

  const float qscale = 0.125f * 1.44269504f;  // 1/sqrt(64) * log2(e)
  dim3 gq(24, 64);  // 1536 blocks
  gemm_qkv<<<gq, 256, 0, stream>>>(xb, fb, wqkvt, bq, bk, bv, m01,
                                   Qb, Kb, Vtb, qscale);

  dim3 ga(16, 64);  // 1024 blocks
  attn_fwd9<<<ga, 256, 0, stream>>>(Qb, Kb, Vtb, m01, AO);

  dim3 go(8, 64);   // 512 blocks
  gemm_out<<<go, 256, 0, stream>>>(AO, wot, bo, out);
}

// Round 15
// 215.497 us; speedup vs baseline: 1.2652x; 1.0161x over previous
//
#include <hip/hip_runtime.h>
#include <stdint.h>
#include <type_traits>

typedef __attribute__((ext_vector_type(8))) short bf16x8;
typedef __attribute__((ext_vector_type(4))) float f32x4;
typedef __attribute__((ext_vector_type(16))) float f32x16;

#define BB 4
#define NH 16
#define TT 2048
#define HD 64
#define CC 1024

__device__ __forceinline__ unsigned short f2bf(float f) {
  unsigned int u = __builtin_bit_cast(unsigned int, f);
  u += 0x7fff + ((u >> 16) & 1);
  return (unsigned short)(u >> 16);
}

__device__ __forceinline__ float fast_exp2(float x) {
#if __has_builtin(__builtin_amdgcn_exp2f)
  return __builtin_amdgcn_exp2f(x);
#else
  return exp2f(x);
#endif
}

__device__ __forceinline__ unsigned int cvtpk(float lo, float hi) {
  unsigned int r;
  asm("v_cvt_pk_bf16_f32 %0, %1, %2" : "=v"(r) : "v"(lo), "v"(hi));
  return r;
}

__device__ __forceinline__ void plswap(unsigned int& a, unsigned int& b) {
#if __has_builtin(__builtin_amdgcn_permlane32_swap)
  auto r = __builtin_amdgcn_permlane32_swap(a, b, false, false);
  a = r[0];
  b = r[1];
#else
  unsigned int as = __shfl_xor((int)a, 32), bs = __shfl_xor((int)b, 32);
  bool hi = (threadIdx.x & 32) != 0;
  unsigned int na = hi ? bs : a;
  unsigned int nb = hi ? b : as;
  a = na; b = nb;
#endif
}

__device__ __forceinline__ float partner32(float x, bool hi) {
  unsigned int a = __builtin_bit_cast(unsigned int, x), b = a;
  plswap(a, b);
  return __builtin_bit_cast(float, hi ? a : b);
}

__device__ __forceinline__ void g2l16(const void* g, void* s) {
  __builtin_amdgcn_global_load_lds(
      (const __attribute__((address_space(1))) unsigned int*)g,
      (__attribute__((address_space(3))) unsigned int*)s, 16, 0, 0);
}

// ---------------- fused prep: casts + weight transposes + mask -------------
// blocks [0,16384): cast x/ft f32->bf16 (1024 elems/block)
// blocks [16384,20480): weight transpose+cast, 32x32 tiles, 4 weights
// blocks [20480,20512): mask int -> float 0/1
__global__ __launch_bounds__(256) void prep_fused(
    const float* __restrict__ x, const float* __restrict__ ft,
    const float* __restrict__ wq, const float* __restrict__ wk,
    const float* __restrict__ wv, const float* __restrict__ wo,
    const int* __restrict__ mask,
    unsigned short* __restrict__ xb, unsigned short* __restrict__ fb,
    unsigned short* __restrict__ wqkvt, unsigned short* __restrict__ wot,
    float* __restrict__ m01) {
  __shared__ float tile[32][33];
  const int bid = blockIdx.x, t = threadIdx.x;
  if (bid < 16384) {
    const float* in = (bid >> 13) ? ft : x;
    unsigned short* out = (bid >> 13) ? fb : xb;
    int i = ((bid & 8191) * 256 + t) * 4;
    float4 v = *(const float4*)(in + i);
    ushort4 o;
    o.x = f2bf(v.x); o.y = f2bf(v.y); o.z = f2bf(v.z); o.w = f2bf(v.w);
    *(ushort4*)(out + i) = o;
  } else if (bid < 20480) {
    const int bid2 = bid - 16384;
    const int z = bid2 >> 10, rem = bid2 & 1023;
    const float* w = (z == 0) ? wq : (z == 1) ? wk : (z == 2) ? wv : wo;
    unsigned short* wt = (z < 3) ? wqkvt + (size_t)z * CC * CC : wot;
    const int nb = (rem & 31) * 32, kb = (rem >> 5) * 32;
    const int tx = t & 31, ty = t >> 5;
#pragma unroll
    for (int r = ty; r < 32; r += 8)
      tile[r][tx] = w[(size_t)(kb + r) * CC + nb + tx];
    __syncthreads();
#pragma unroll
    for (int r = ty; r < 32; r += 8)
      wt[(size_t)(nb + r) * CC + kb + tx] = f2bf(tile[tx][r]);
  } else {
    int i = (bid - 20480) * 256 + t;
    m01[i] = mask[i] ? 1.0f : 0.0f;
  }
}

// ---------------- fused QKV GEMM: r12 form (BK=32, 16KB, chunk swizzle) ----
__global__ __launch_bounds__(256) void gemm_qkv(
    const unsigned short* __restrict__ xb, const unsigned short* __restrict__ fb,
    const unsigned short* __restrict__ Wt,
    const float* __restrict__ bq, const float* __restrict__ bk,
    const float* __restrict__ bv, const float* __restrict__ m01,
    unsigned short* __restrict__ Qb, unsigned short* __restrict__ Kb,
    unsigned short* __restrict__ Vtb, float qscale) {
  __shared__ unsigned short As[128 * 32];
  __shared__ unsigned short Bs[128 * 32];
  int lin = blockIdx.y * gridDim.x + blockIdx.x;
  int cpx = (gridDim.x * gridDim.y) >> 3;
  int sw = (lin & 7) * cpx + (lin >> 3);
  const int n0g = (sw % 24) * 128;
  const int m0 = (sw / 24) * 128;
  const int sec = n0g >> 10;
  const int n0 = n0g & (CC - 1);
  const unsigned short* A = (sec == 0) ? xb : fb;
  const unsigned short* Bt = Wt + (size_t)n0g * CC;

  const int t = threadIdx.x, l = t & 63, w = t >> 6;
  const int lr = l & 15, lg = l >> 4;
  const int wr = w >> 1, wc = w & 1;

  const int c1 = t + 256;
  const int r0 = t >> 2, k0e = (((t & 3) ^ (r0 & 3)) * 8);
  const int r1 = c1 >> 2, k1e = (((c1 & 3) ^ (r1 & 3)) * 8);
  const unsigned short* gA0 = A + (size_t)(m0 + r0) * CC + k0e;
  const unsigned short* gA1 = A + (size_t)(m0 + r1) * CC + k1e;
  const unsigned short* gB0 = Bt + (size_t)r0 * CC + k0e;
  const unsigned short* gB1 = Bt + (size_t)r1 * CC + k1e;
  auto stage = [&]() {
    g2l16(gA0, (char*)As + t * 16);
    g2l16(gA1, (char*)As + t * 16 + 4096);
    g2l16(gB0, (char*)Bs + t * 16);
    g2l16(gB1, (char*)Bs + t * 16 + 4096);
    gA0 += 32; gA1 += 32; gB0 += 32; gB1 += 32;
  };

  const int colx = (lg * 16) ^ ((lr & 3) << 4);
  const int abase = (wr * 64 + lr) * 64 + colx;
  const int bbase = (wc * 64 + lr) * 64 + colx;

  f32x4 acc[4][4] = {};
  for (int j = 0; j < 32; ++j) {
    stage();
    asm volatile("s_waitcnt vmcnt(0)" ::: "memory");
    __syncthreads();
    bf16x8 af[4], bfr[4];
#pragma unroll
    for (int mi = 0; mi < 4; ++mi)
      af[mi] = *(const bf16x8*)((const char*)As + abase + mi * 1024);
#pragma unroll
    for (int nj = 0; nj < 4; ++nj)
      bfr[nj] = *(const bf16x8*)((const char*)Bs + bbase + nj * 1024);
#pragma unroll
    for (int mi = 0; mi < 4; ++mi)
#pragma unroll
      for (int nj = 0; nj < 4; ++nj)
        acc[mi][nj] = __builtin_amdgcn_mfma_f32_16x16x32_bf16(
            af[mi], bfr[nj], acc[mi][nj], 0, 0, 0);
    __syncthreads();
  }

  if (sec < 2) {
    const float* bp = (sec == 0) ? bq : bk;
    const float scale = (sec == 0) ? qscale : 1.0f;
    unsigned short* dst = (sec == 0) ? Qb : Kb;
#pragma unroll
    for (int mi = 0; mi < 4; ++mi) {
#pragma unroll
      for (int nj = 0; nj < 4; ++nj) {
        int col = n0 + wc * 64 + nj * 16 + lr;
        float bias = bp[col];
#pragma unroll
        for (int j = 0; j < 4; ++j) {
          int rowm = m0 + wr * 64 + mi * 16 + lg * 4 + j;
          float v = (acc[mi][nj][j] + bias) * scale;
          int b_ = rowm >> 11, tq = rowm & (TT - 1);
          int h_ = col >> 6, d_ = col & (HD - 1);
          dst[((size_t)((b_ * NH + h_) * TT + tq) << 6) + d_] = f2bf(v);
        }
      }
    }
  } else {
#pragma unroll
    for (int mi = 0; mi < 4; ++mi) {
      int rowb = m0 + wr * 64 + mi * 16 + lg * 4;
      int b_ = rowb >> 11, tq = rowb & (TT - 1);
      f32x4 mv = *(const f32x4*)(m01 + rowb);
#pragma unroll
      for (int nj = 0; nj < 4; ++nj) {
        int col = n0 + wc * 64 + nj * 16 + lr;
        float bias = bv[col];
        int h_ = col >> 6, d_ = col & (HD - 1);
        unsigned short pk[4];
#pragma unroll
        for (int j = 0; j < 4; ++j)
          pk[j] = f2bf((acc[mi][nj][j] + bias) * mv[j]);
        *(ushort4*)(Vtb + ((size_t)((b_ * NH + h_) * HD + d_) << 11) + tq) =
            *(ushort4*)pk;
      }
    }
  }
}

// ---------------- O-projection GEMM: BK=64, swizzled LDS (r11 form) --------
__global__ __launch_bounds__(256) void gemm_out(
    const unsigned short* __restrict__ A, const unsigned short* __restrict__ Bt,
    const float* __restrict__ bias, float* __restrict__ Out) {
  __shared__ unsigned short As[128 * 64];
  __shared__ unsigned short Bs[128 * 64];
  int lin = blockIdx.y * gridDim.x + blockIdx.x;
  int cpx = (gridDim.x * gridDim.y) >> 3;
  int sw = (lin & 7) * cpx + (lin >> 3);
  const int n0 = (sw % 8) * 128;
  const int m0 = (sw / 8) * 128;
  const int t = threadIdx.x, l = t & 63, w = t >> 6;
  const int lr = l & 15, lg = l >> 4;
  const int wr = w >> 1, wc = w & 1;

  const int sR = t >> 3;
  const int sx = ((t & 7) * 16) ^ ((sR & 7) << 4);
  const unsigned short* gA = A + (size_t)(m0 + sR) * CC + (sx >> 1);
  const unsigned short* gB = Bt + (size_t)(n0 + sR) * CC + (sx >> 1);
  auto stage = [&]() {
#pragma unroll
    for (int i = 0; i < 4; ++i) {
      g2l16(gA + (size_t)(i * 32) * CC, (char*)As + t * 16 + i * 4096);
      g2l16(gB + (size_t)(i * 32) * CC, (char*)Bs + t * 16 + i * 4096);
    }
    gA += 64; gB += 64;
  };

  const int axs = (lr & 7) << 4;
  const int col0 = (lg * 16) ^ axs;
  const int col1 = (64 + lg * 16) ^ axs;
  const int abase = (wr * 64 + lr) * 128;
  const int bbase = (wc * 64 + lr) * 128;

  f32x4 acc[4][4] = {};
  for (int j = 0; j < 16; ++j) {
    stage();
    asm volatile("s_waitcnt vmcnt(0)" ::: "memory");
    __syncthreads();
    bf16x8 af[4], bfr[4];
#pragma unroll
    for (int mi = 0; mi < 4; ++mi)
      af[mi] = *(const bf16x8*)((const char*)As + abase + mi * 2048 + col0);
#pragma unroll
    for (int nj = 0; nj < 4; ++nj)
      bfr[nj] = *(const bf16x8*)((const char*)Bs + bbase + nj * 2048 + col0);
#pragma unroll
    for (int mi = 0; mi < 4; ++mi)
#pragma unroll
      for (int nj = 0; nj < 4; ++nj)
        acc[mi][nj] = __builtin_amdgcn_mfma_f32_16x16x32_bf16(
            af[mi], bfr[nj], acc[mi][nj], 0, 0, 0);
#pragma unroll
    for (int mi = 0; mi < 4; ++mi)
      af[mi] = *(const bf16x8*)((const char*)As + abase + mi * 2048 + col1);
#pragma unroll
    for (int nj = 0; nj < 4; ++nj)
      bfr[nj] = *(const bf16x8*)((const char*)Bs + bbase + nj * 2048 + col1);
#pragma unroll
    for (int mi = 0; mi < 4; ++mi)
#pragma unroll
      for (int nj = 0; nj < 4; ++nj)
        acc[mi][nj] = __builtin_amdgcn_mfma_f32_16x16x32_bf16(
            af[mi], bfr[nj], acc[mi][nj], 0, 0, 0);
    __syncthreads();
  }

#pragma unroll
  for (int mi = 0; mi < 4; ++mi) {
#pragma unroll
    for (int nj = 0; nj < 4; ++nj) {
      int col = n0 + wc * 64 + nj * 16 + lr;
      float bv = bias[col];
#pragma unroll
      for (int j = 0; j < 4; ++j) {
        int rowm = m0 + wr * 64 + mi * 16 + lg * 4 + j;
        Out[(size_t)rowm * CC + col] = acc[mi][nj][j] + bv;
      }
    }
  }
}

// ---------------- flash attention v9 (r13 known-good, unchanged) -----------
__global__ __launch_bounds__(256) void attn_fwd9(
    const unsigned short* __restrict__ Q, const unsigned short* __restrict__ K,
    const unsigned short* __restrict__ Vt, const float* __restrict__ m01,
    unsigned short* __restrict__ O) {
  __shared__ __attribute__((aligned(64))) char ldsb[40960];
  const int t = threadIdx.x, l = t & 63, w = t >> 6;
  const int q5 = l & 31, hig = l >> 5;
  const bool hib = hig != 0;
  int lin = blockIdx.y * gridDim.x + blockIdx.x;
  int sw = (lin & 7) * 128 + (lin >> 3);
  const int bx = sw & 15, bh = sw >> 4;
  const int b_ = bh >> 4, h_ = bh & (NH - 1);
  const int q = bx * 128 + w * 32 + q5;
  const size_t base = (size_t)bh * TT * HD;
  const unsigned short* Kg = K + base;
  const unsigned short* Vg = Vt + (size_t)bh * HD * TT;

  bf16x8 qf[4];
  {
    const unsigned short* qp = Q + base + (size_t)q * HD + 8 * hig;
#pragma unroll
    for (int dk = 0; dk < 4; ++dk) qf[dk] = *(const bf16x8*)(qp + dk * 16);
  }

  int ka[4];
  {
    int swz = (q5 & 7) << 4;
#pragma unroll
    for (int dk = 0; dk < 4; ++dk)
      ka[dk] = q5 * 128 + ((dk * 32 + hig * 16) ^ swz);
  }
  int moff = 32768 + hig * 16;

  const int s1 = t + 256;
  const int r0 = t >> 3, c0 = (t & 7) * 16, x0 = c0 ^ ((r0 & 7) << 4);
  const int r1 = s1 >> 3, c1 = (s1 & 7) * 16, x1 = c1 ^ ((r1 & 7) << 4);
  const unsigned short* gk0 = Kg + r0 * HD + (x0 >> 1);
  const unsigned short* gk1 = Kg + r1 * HD + (x1 >> 1);
  const unsigned short* gv0 = Vg + (size_t)r0 * TT + (x0 >> 1);
  const unsigned short* gv1 = Vg + (size_t)r1 * TT + (x1 >> 1);

  auto stage = [&](int boff) {
    g2l16(gk0, ldsb + t * 16 + boff);
    g2l16(gk1, ldsb + t * 16 + 4096 + boff);
    g2l16(gv0, ldsb + 16384 + t * 16 + boff);
    g2l16(gv1, ldsb + 16384 + t * 16 + 4096 + boff);
    gk0 += 4096; gk1 += 4096; gv0 += 64; gv1 += 64;
  };

  f32x16 ot[2];
#pragma unroll
  for (int i = 0; i < 16; ++i) { ot[0][i] = 0.f; ot[1][i] = 0.f; }
  float l0 = 0.f, l1 = 0.f, l2 = 0.f, l3 = 0.f;

  {
    const float* mg = m01 + (size_t)b_ * TT;
#pragma unroll
    for (int i = 0; i < 2; ++i) {
      int s = t + i * 256;
      g2l16(mg + s * 4, ldsb + 32768 + s * 16);
    }
  }
  stage(0);
  asm volatile("s_waitcnt vmcnt(0)" ::: "memory");
  __syncthreads();

  auto compute = [&](auto Bc) {
    constexpr int BO = decltype(Bc)::value;
    constexpr int MO = BO ? 256 : 0;
#pragma unroll
    for (int kk = 0; kk < 2; ++kk) {
      f32x16 s = {};
      __builtin_amdgcn_s_setprio(1);
#pragma unroll
      for (int dk = 0; dk < 4; ++dk) {
        bf16x8 kf = *(const bf16x8*)(ldsb + ka[dk] + kk * 4096 + BO);
        s = __builtin_amdgcn_mfma_f32_32x32x16_bf16(kf, qf[dk], s, 0, 0, 0);
      }
      __builtin_amdgcn_s_setprio(0);

      unsigned int wl[4], wh[4];
#pragma unroll
      for (int g = 0; g < 4; ++g) {
        int i = g * 4;
        float e0 = fast_exp2(s[i + 0]);
        float e1 = fast_exp2(s[i + 1]);
        float e2 = fast_exp2(s[i + 2]);
        float e3 = fast_exp2(s[i + 3]);
        f32x4 mk = *(const f32x4*)(ldsb + moff + MO + kk * 128 + g * 32);
        l0 = fmaf(e0, mk[0], l0);
        l1 = fmaf(e1, mk[1], l1);
        l2 = fmaf(e2, mk[2], l2);
        l3 = fmaf(e3, mk[3], l3);
        wl[g] = cvtpk(e0, e1);
        wh[g] = cvtpk(e2, e3);
      }

      bf16x8 pa[2];
#pragma unroll
      for (int kh = 0; kh < 2; ++kh) {
        const int gA = 2 * kh, gB = gA + 1;
        unsigned int a0 = wl[gA], b0 = wl[gB];
        unsigned int a1 = wh[gA], b1 = wh[gB];
        plswap(a0, b0);
        plswap(a1, b1);
        unsigned int pw[4] = {a0, a1, b0, b1};
        pa[kh] = *(bf16x8*)pw;
      }

      __builtin_amdgcn_s_setprio(1);
#pragma unroll
      for (int kh = 0; kh < 2; ++kh) {
        const int ks = kk * 2 + kh;
        bf16x8 vf0 = *(const bf16x8*)(ldsb + ka[ks] + 16384 + BO);
        bf16x8 vf1 = *(const bf16x8*)(ldsb + ka[ks] + 16384 + 4096 + BO);
        ot[0] = __builtin_amdgcn_mfma_f32_32x32x16_bf16(vf0, pa[kh], ot[0], 0, 0, 0);
        ot[1] = __builtin_amdgcn_mfma_f32_32x32x16_bf16(vf1, pa[kh], ot[1], 0, 0, 0);
      }
      __builtin_amdgcn_s_setprio(0);
    }
  };

  for (int j = 0; j < 16; ++j) {
    stage(8192);
    compute(std::integral_constant<int, 0>{});
    asm volatile("s_waitcnt vmcnt(0)" ::: "memory");
    __syncthreads();
    if (j < 15) stage(0);
    compute(std::integral_constant<int, 8192>{});
    asm volatile("s_waitcnt vmcnt(0)" ::: "memory");
    __syncthreads();
    moff += 512;
  }

  float l_ = (l0 + l1) + (l2 + l3);
  float l_tot = l_ + partner32(l_, hib);
  const float inv = 1.f / l_tot;
  unsigned short* orow = O + ((size_t)(b_ * TT) + q) * CC + h_ * 64 + 4 * hig;
#pragma unroll
  for (int dt = 0; dt < 2; ++dt)
#pragma unroll
    for (int g = 0; g < 4; ++g) {
      unsigned short pk4[4];
#pragma unroll
      for (int j = 0; j < 4; ++j) pk4[j] = f2bf(ot[dt][4 * g + j] * inv);
      *(ushort4*)(orow + dt * 32 + 8 * g) = *(ushort4*)pk4;
    }
}

extern "C" void kernel_launch(void* const* d_in, const int* in_sizes, int n_in,
                              void* d_out, int out_size, void* d_ws, size_t ws_size,
                              hipStream_t stream) {
  const float* x  = (const float*)d_in[0];
  const float* ft = (const float*)d_in[1];
  const int* mask = (const int*)d_in[2];
  const float* wq = (const float*)d_in[3];
  const float* bq = (const float*)d_in[4];
  const float* wk = (const float*)d_in[5];
  const float* bk = (const float*)d_in[6];
  const float* wv = (const float*)d_in[7];
  const float* bv = (const float*)d_in[8];
  const float* wo = (const float*)d_in[9];
  const float* bo = (const float*)d_in[10];
  float* out = (float*)d_out;

  char* ws = (char*)d_ws;
  const size_t NTOK = (size_t)BB * TT;   // 8192
  const size_t SB = NTOK * CC * 2;       // 16 MiB
  unsigned short* xb   = (unsigned short*)ws; ws += SB;
  unsigned short* fb   = (unsigned short*)ws; ws += SB;
  unsigned short* Qb   = (unsigned short*)ws; ws += SB;
  unsigned short* Kb   = (unsigned short*)ws; ws += SB;
  unsigned short* Vtb  = (unsigned short*)ws; ws += SB;   // V^T (b,h,d,t)
  unsigned short* AO   = (unsigned short*)ws; ws += SB;
  unsigned short* wqkvt = (unsigned short*)ws; ws += (size_t)3 * CC * CC * 2;
  unsigned short* wot   = (unsigned short*)ws; ws += (size_t)CC * CC * 2;
  float* m01 = (float*)ws; ws += NTOK * 4;

  prep_fused<<<20512, 256, 0, stream>>>(x, ft, wq, wk, wv, wo, mask,
                                        xb, fb, wqkvt, wot, m01);

  const float qscale = 0.125f * 1.44269504f;  // 1/sqrt(64) * log2(e)
  dim3 gq(24, 64);  // 1536 blocks
  gemm_qkv<<<gq, 256, 0, stream>>>(xb, fb, wqkvt, bq, bk, bv, m01,
                                   Qb, Kb, Vtb, qscale);

  dim3 ga(16, 64);  // 1024 blocks
  attn_fwd9<<<ga, 256, 0, stream>>>(Qb, Kb, Vtb, m01, AO);

  dim3 go(8, 64);   // 512 blocks
  gemm_out<<<go, 256, 0, stream>>>(AO, wot, bo, out);
}